// Round 6
// baseline (1025.129 us; speedup 1.0000x reference)
//
#include <hip/hip_runtime.h>
#include <hip/hip_bf16.h>
#include <math.h>

// Gated Slot Attention. Inputs f32, output f32.
// ROUND 14: R13's T14 prefetch SPILLED (VGPR capped at 128 by default
// launch_bounds occupancy heuristic -> +93MB scratch WRITE, +62MB FETCH,
// scan 152->200us). Kernel is LDS-bound to 1 blk/CU (2 waves/SIMD), so the
// VGPR cap bought nothing. Fix: __launch_bounds__(512,1) on gsa_chunk_t &
// gsa_segA -> allocator free to ~256 VGPR, no spill, occupancy unchanged.

typedef __bf16 bf16x8 __attribute__((ext_vector_type(8)));
typedef float f32x4 __attribute__((ext_vector_type(4)));

#define ROWS 8192   // B*T
#define DM 2048

#define MODE_F32 0
#define MODE_SWISH 1
#define MODE_GATE 2

// LDS bank-conflict swizzle for the scan buffers (stride 72/264 shorts).
#define XS(r, c) ((c) ^ ((r) & 56))

__device__ __forceinline__ float u2f(unsigned short u) {
  union { unsigned int i; float f; } cv; cv.i = ((unsigned int)u) << 16; return cv.f;
}
__device__ __forceinline__ unsigned short f2us(float f) {
  return __builtin_bit_cast(unsigned short, __float2bfloat16(f));
}
__device__ __forceinline__ float swishf(float v) { return v / (1.f + expf(-v)); }

// async global->LDS, 16B per lane; LDS dest = wave-uniform base + lane*16.
__device__ __forceinline__ void gload16(const void* g, void* l) {
  __builtin_amdgcn_global_load_lds(
      (const __attribute__((address_space(1))) void*)g,
      (__attribute__((address_space(3))) void*)l, 16, 0, 0);
}

// --------------------------------------------------------------- xnorm ---
__global__ __launch_bounds__(256) void xnorm_kernel(
    const float* __restrict__ in, const float* __restrict__ w,
    unsigned short* __restrict__ out)
{
  const int row = blockIdx.x, tid = threadIdx.x;
  const size_t base = (size_t)row * DM + tid * 8;
  float a[8];
#pragma unroll
  for (int i = 0; i < 8; ++i) a[i] = in[base + i];
  float ss = 0.f;
#pragma unroll
  for (int i = 0; i < 8; ++i) ss += a[i] * a[i];
#pragma unroll
  for (int off = 32; off; off >>= 1) ss += __shfl_xor(ss, off, 64);
  __shared__ float wsum[4];
  if ((tid & 63) == 0) wsum[tid >> 6] = ss;
  __syncthreads();
  float tot = wsum[0] + wsum[1] + wsum[2] + wsum[3];
  float rstd = rsqrtf(tot * (1.f / (float)DM) + 1e-5f);
#pragma unroll
  for (int i = 0; i < 8; ++i)
    out[base + i] = f2us(a[i] * rstd * w[tid * 8 + i]);
}

// ---------------------------------------------------------- oact_norm ---
__global__ __launch_bounds__(256) void oact_norm_kernel(
    const float* __restrict__ o, const float* __restrict__ w,
    unsigned short* __restrict__ out)
{
  const int row = blockIdx.x, tid = threadIdx.x;
  const size_t base = (size_t)row * DM + tid * 8;
  float a[8];
#pragma unroll
  for (int i = 0; i < 8; ++i) a[i] = swishf(o[base + i]);
  float ss = 0.f;
#pragma unroll
  for (int i = 0; i < 8; ++i) ss += a[i] * a[i];
#pragma unroll
  for (int off = 32; off; off >>= 1) ss += __shfl_xor(ss, off, 64);
  __shared__ float wsum[4];
  if ((tid & 63) == 0) wsum[tid >> 6] = ss;
  __syncthreads();
  float tot = wsum[0] + wsum[1] + wsum[2] + wsum[3];
  float rstd = rsqrtf(tot * (1.f / (float)DM) + 1e-5f);
#pragma unroll
  for (int i = 0; i < 8; ++i)
    out[base + i] = f2us(a[i] * rstd * w[tid * 8 + i]);
}

// -------------------------------------------------- weight f32->bf16 ---
__global__ __launch_bounds__(256) void wconv_kernel(
    const float* __restrict__ in, unsigned short* __restrict__ out)
{
  size_t i = ((size_t)blockIdx.x * 256 + threadIdx.x) * 8;
  float4 a = *(const float4*)(in + i);
  float4 b = *(const float4*)(in + i + 4);
  unsigned short u[8] = {f2us(a.x), f2us(a.y), f2us(a.z), f2us(a.w),
                         f2us(b.x), f2us(b.y), f2us(b.z), f2us(b.w)};
  *(uint4*)(out + i) = *(const uint4*)u;
}

// ------------------------------------------- MFMA GEMM v2 (glds) ---
// C[m,n] = epilogue( sum_k A[m,k]*WB[n,k] ); A,WB bf16 row-major K=2048.
// 128x128 tile, BK=32, 2x2 waves of 64x64, 16x16x32 bf16 MFMA.
// LDS tile linear (glds dest); chunk swizzle cb^=(row>>1)&3 applied on
// the GLOBAL source and on reads. XCD chunk swizzle on blockIdx.
__global__ __launch_bounds__(256) void mgemm2_kernel(
    const unsigned short* __restrict__ A, const unsigned short* __restrict__ WB,
    unsigned short* __restrict__ outB, float* __restrict__ outF,
    int N, int mode)
{
  __shared__ __align__(16) unsigned short As[128 * 32];
  __shared__ __align__(16) unsigned short Bs[128 * 32];
  const int tid = threadIdx.x;
  // XCD chunk swizzle: nwg (1024 or 256) divisible by 8 -> bijective.
  const int bid = (int)(blockIdx.y * gridDim.x + blockIdx.x);
  const int nwg = (int)(gridDim.x * gridDim.y);
  const int cpx = nwg >> 3;
  const int swz = (bid & 7) * cpx + (bid >> 3);
  const int bn = swz % (int)gridDim.x, bm = swz / (int)gridDim.x;
  const int w = tid >> 6, l = tid & 63;
  const int wm = w & 1, wn = w >> 1;
  const int fr = l & 15, fq = l >> 4;

  f32x4 acc[4][4];
#pragma unroll
  for (int i = 0; i < 4; ++i)
#pragma unroll
    for (int j = 0; j < 4; ++j) acc[i][j] = (f32x4){0.f, 0.f, 0.f, 0.f};

  // staging geometry: physical chunk p = w*128 + j*64 + l
  int prow[2], pcol[2];
#pragma unroll
  for (int j = 0; j < 2; ++j) {
    int p = w * 128 + j * 64 + l;
    prow[j] = p >> 2;
    pcol[j] = ((p & 3) ^ ((prow[j] >> 1) & 3)) * 8;  // element offset in row
  }
  const size_t abase = (size_t)(bm * 128) * DM;
  const size_t bbase = (size_t)(bn * 128) * DM;

  for (int k0 = 0; k0 < DM; k0 += 32) {
#pragma unroll
    for (int j = 0; j < 2; ++j) {
      gload16(A + abase + (size_t)prow[j] * DM + k0 + pcol[j],
              &As[(w * 128 + j * 64) * 8]);
      gload16(WB + bbase + (size_t)prow[j] * DM + k0 + pcol[j],
              &Bs[(w * 128 + j * 64) * 8]);
    }
    __syncthreads();
    bf16x8 af[4], bfr[4];
#pragma unroll
    for (int i = 0; i < 4; ++i) {
      int row = wm * 64 + i * 16 + fr;
      af[i] = *(const bf16x8*)&As[row * 32 + ((fq ^ ((row >> 1) & 3)) * 8)];
    }
#pragma unroll
    for (int j = 0; j < 4; ++j) {
      int row = wn * 64 + j * 16 + fr;
      bfr[j] = *(const bf16x8*)&Bs[row * 32 + ((fq ^ ((row >> 1) & 3)) * 8)];
    }
#pragma unroll
    for (int i = 0; i < 4; ++i)
#pragma unroll
      for (int j = 0; j < 4; ++j)
        acc[i][j] = __builtin_amdgcn_mfma_f32_16x16x32_bf16(af[i], bfr[j], acc[i][j], 0, 0, 0);
    __syncthreads();
  }

#pragma unroll
  for (int i = 0; i < 4; ++i) {
#pragma unroll
    for (int rr = 0; rr < 4; ++rr) {
      int row = bm * 128 + wm * 64 + i * 16 + fq * 4 + rr;
#pragma unroll
      for (int j = 0; j < 4; ++j) {
        int col = bn * 128 + wn * 64 + j * 16 + fr;
        float val = acc[i][j][rr];
        size_t idx = (size_t)row * N + col;
        if (mode == MODE_SWISH)      outB[idx] = f2us(swishf(val));
        else if (mode == MODE_F32)   outF[idx] = val;
        else {  // MODE_GATE
          float ls = fminf(val, 0.f) - log1pf(expf(-fabsf(val)));
          outF[idx] = ls * 0.125f;
        }
      }
    }
  }
}

// ------------------------------------------------------------ MFMA GEMM ---
// (fallback tier: W in f32, converted in-kernel)
#define BM 128
#define BN 128
#define BK 32
#define LDSP 40

__global__ __launch_bounds__(256) void mgemm_kernel(
    const unsigned short* __restrict__ A, const float* __restrict__ W,
    unsigned short* __restrict__ outB, float* __restrict__ outF,
    int N, int mode)
{
  __shared__ __align__(16) unsigned short As[BM][LDSP];
  __shared__ __align__(16) unsigned short Bs[BN][LDSP];
  const int bn = blockIdx.x, bm = blockIdx.y, tid = threadIdx.x;
  const int w = tid >> 6, l = tid & 63;
  const int wm = w & 1, wn = w >> 1;
  const int fr = l & 15, fq = l >> 4;

  f32x4 acc[4][4];
#pragma unroll
  for (int i = 0; i < 4; ++i)
#pragma unroll
    for (int j = 0; j < 4; ++j) acc[i][j] = (f32x4){0.f, 0.f, 0.f, 0.f};

  for (int k0 = 0; k0 < DM; k0 += BK) {
#pragma unroll
    for (int s = 0; s < 2; ++s) {
      int chunk = tid + s * 256;
      int row = chunk >> 2;
      int cc = (chunk & 3) * 8;
      *(uint4*)&As[row][cc] =
          *(const uint4*)(A + (size_t)(bm * BM + row) * DM + k0 + cc);
    }
#pragma unroll
    for (int s = 0; s < 4; ++s) {
      int chunk = tid + s * 256;
      int row = chunk >> 3;
      int cc = (chunk & 7) * 4;
      float4 wv = *(const float4*)(W + (size_t)(bn * BN + row) * DM + k0 + cc);
      ushort4 w4;
      w4.x = f2us(wv.x); w4.y = f2us(wv.y); w4.z = f2us(wv.z); w4.w = f2us(wv.w);
      *(ushort4*)&Bs[row][cc] = w4;
    }
    __syncthreads();
    bf16x8 af[4], bfr[4];
#pragma unroll
    for (int i = 0; i < 4; ++i) af[i] = *(const bf16x8*)&As[wm * 64 + i * 16 + fr][fq * 8];
#pragma unroll
    for (int j = 0; j < 4; ++j) bfr[j] = *(const bf16x8*)&Bs[wn * 64 + j * 16 + fr][fq * 8];
#pragma unroll
    for (int i = 0; i < 4; ++i)
#pragma unroll
      for (int j = 0; j < 4; ++j)
        acc[i][j] = __builtin_amdgcn_mfma_f32_16x16x32_bf16(af[i], bfr[j], acc[i][j], 0, 0, 0);
    __syncthreads();
  }

#pragma unroll
  for (int i = 0; i < 4; ++i) {
#pragma unroll
    for (int rr = 0; rr < 4; ++rr) {
      int row = bm * BM + wm * 64 + i * 16 + fq * 4 + rr;
#pragma unroll
      for (int j = 0; j < 4; ++j) {
        int col = bn * BN + wn * 64 + j * 16 + fr;
        float val = acc[i][j][rr];
        size_t idx = (size_t)row * N + col;
        if (mode == MODE_SWISH)      outB[idx] = f2us(swishf(val));
        else if (mode == MODE_F32)   outF[idx] = val;
        else {  // MODE_GATE
          float ls = fminf(val, 0.f) - log1pf(expf(-fabsf(val)));
          outF[idx] = ls * 0.125f;
        }
      }
    }
  }
}

// ------------------------------------------------ Chunked GSA scan (C) ---
// Template: NCH chunks per block; INIT loads gk/gv from Sinit (f32).
// Fallback = <32,false>, grid 32.  Phase C = <4,true>, grid 256.
// T14: chunk c+1's Q/K/G prefetched to regs after ph2; V after ph8.
// launch_bounds(512,1): LDS-bound to 1 blk/CU anyway; free the VGPRs.
template<int NCH, bool INIT>
__global__ __launch_bounds__(512, 1) void gsa_chunk_t(
    const unsigned short* __restrict__ Q, const unsigned short* __restrict__ K,
    const unsigned short* __restrict__ V, const float* __restrict__ G,
    float* __restrict__ O, const float* __restrict__ DK,
    const float* __restrict__ DV)
{
  // ---- LDS pool, phase-multiplexed (155.1 KiB) ----
  __shared__ __align__(16) char pool[158848];
  auto EB   = (unsigned short(*)[72])(pool + 0);       // e[i][m] bf16 (no XS)
  auto O1B  = (unsigned short(*)[72])(pool + 9216);    // o1[i][m] -> (GvB2 low)
  auto RB   = (unsigned short(*)[72])(pool + 18432);   // r[tau][m] -> (GvB2 hi)
  auto RT   = (unsigned short(*)[72])(pool + 27648);   // r^T[m][tau] -> wT
  auto SB   = (unsigned short(*)[72])(pool + 36864);   // S[i][tau] -> P[i][tau]
  auto UB   = (unsigned short(*)[72])(pool + 46080);   // u[i][m]
  float (*GS)[64] = (float(*)[64])(pool + 55296);      // g staging (f32)
  auto QT   = (unsigned short(*)[264])(pool + 55296);  // q tile [i][d]
  auto KTt2 = (unsigned short(*)[72])(pool + 55296);   // k^T rows d-128
  auto VTt2 = (unsigned short(*)[72])(pool + 55296);   // v^T rows u-128
  auto KT   = (unsigned short(*)[264])(pool + 89088);  // k tile [tau][d]
  auto VTt1 = (unsigned short(*)[72])(pool + 89088);   // v^T rows u<128
  auto GkB  = (unsigned short(*)[264])(pool + 122880); // Gk snapshot [m][d]
  auto KTt1 = (unsigned short(*)[72])(pool + 122880);  // k^T rows d<128
  auto GvB1 = (unsigned short(*)[72])(pool + 122880);  // Gv snapshot u<128
  auto GvB2 = (unsigned short(*)[72])(pool + 9216);    // Gv snapshot u>=128
  float (*red)[68] = (float(*)[68])(pool + 156672);    // prefix partials

  int bh, seg;
  if constexpr (INIT) { bh = (int)blockIdx.x >> 3; seg = (int)blockIdx.x & 7; }
  else                { bh = (int)blockIdx.x; seg = 0; }
  const int b = bh >> 3, h = bh & 7;
  const int tid = threadIdx.x;
  const int w = tid >> 6, l = tid & 63, fr = l & 15, fq = l >> 4;
  const int wlo = w & 3, whi = w >> 2;

  // ---- prefetch registers (layouts mirror the LDS store loops) ----
  float4 pg[2];
  uint4 pq[4], pk[4], pv1[4], pv2[2];
  auto pref_g = [&](int c) {
    const int rb = b * 2048 + c * 64;
#pragma unroll
    for (int s = 0; s < 2; ++s) {
      int id = s * 512 + tid, row = id >> 4, mq = id & 15;
      pg[s] = *(const float4*)&G[(size_t)(rb + row) * 512 + h * 64 + mq * 4];
    }
  };
  auto pref_qk = [&](int c) {
    const int rb = b * 2048 + c * 64;
#pragma unroll
    for (int s = 0; s < 4; ++s) {
      int id = s * 512 + tid, row = id >> 5, cc = (id & 31) * 8;
      size_t gb = (size_t)(rb + row) * 2048 + h * 256 + cc;
      pq[s] = *(const uint4*)(Q + gb);
      pk[s] = *(const uint4*)(K + gb);
    }
  };
  auto pref_v = [&](int c) {
    const int rb = b * 2048 + c * 64;
    if (tid < 256) {
#pragma unroll
      for (int s = 0; s < 4; ++s) {
        int id = s * 256 + tid, u8 = id & 15, tau = id >> 4;
        pv1[s] = *(const uint4*)(V + (size_t)(rb + tau) * 2048 + h * 256 + u8 * 8);
      }
    }
#pragma unroll
    for (int s = 0; s < 2; ++s) {
      int id = s * 512 + tid, u8 = id & 15, tau = id >> 4;
      pv2[s] = *(const uint4*)(V + (size_t)(rb + tau) * 2048 + h * 256 + 128 + u8 * 8);
    }
  };

  // prologue: prefetch chunk 0 of this segment
  pref_g(seg * NCH);
  pref_qk(seg * NCH);
  pref_v(seg * NCH);

  // gk[jj]: (m=wlo*16+fq*4+rr, d=(whi*8+jj)*16+fr)
  // gv[jj]: (u=ut*16+fq*4+rr, m=(jj&3)*16+fr), ut=(w>=4?8:0)+wlo*2+(jj>>2)
  f32x4 gk[8], gv[8];
  if constexpr (INIT) {
    const float* dk = DK + ((size_t)bh * 8 + seg) * 16384;
    const float* dv = DV + ((size_t)bh * 8 + seg) * 16384;
#pragma unroll
    for (int jj = 0; jj < 8; ++jj) {
      int ut = (w >= 4 ? 8 : 0) + wlo * 2 + (jj >> 2);
#pragma unroll
      for (int rr = 0; rr < 4; ++rr) {
        gk[jj][rr] = dk[(wlo * 16 + fq * 4 + rr) * 256 + (whi * 8 + jj) * 16 + fr];
        gv[jj][rr] = dv[(ut * 16 + fq * 4 + rr) * 64 + (jj & 3) * 16 + fr];
      }
    }
  } else {
#pragma unroll
    for (int jj = 0; jj < 8; ++jj) {
      gk[jj] = (f32x4){0.f, 0.f, 0.f, 0.f};
      gv[jj] = (f32x4){0.f, 0.f, 0.f, 0.f};
    }
  }

  for (int cl = 0; cl < NCH; ++cl) {
    const int c = seg * NCH + cl;
    const int rowbase = b * 2048 + c * 64;
    const bool upd = (cl != NCH - 1);  // last chunk's state update is dead

    // ---- ph1a: stage g tile (from regs); write Gk bf16 snapshot ----
#pragma unroll
    for (int s = 0; s < 2; ++s) {
      int id = s * 512 + tid, row = id >> 4, mq = id & 15;
      *(float4*)&GS[row][mq * 4] = pg[s];
    }
#pragma unroll
    for (int jj = 0; jj < 8; ++jj) {
      int dcol = (whi * 8 + jj) * 16 + fr;
#pragma unroll
      for (int rr = 0; rr < 4; ++rr) {
        int grow = wlo * 16 + fq * 4 + rr;
        GkB[grow][XS(grow, dcol)] = f2us(gk[jj][rr]);
      }
    }
    __syncthreads();

    // ---- ph1b: per-8-row partial sums of g (prefix stage 1) ----
    {
      float ps = 0.f;
#pragma unroll
      for (int j = 0; j < 8; ++j) ps += GS[w * 8 + j][l];
      red[w][l] = ps;
    }
    __syncthreads();

    // ---- ph1c: cum, e, r (EB, RB, RT) ----
    {
      float cum = 0.f;
      for (int g2 = 0; g2 < w; ++g2) cum += red[g2][l];
#pragma unroll
      for (int j = 0; j < 8; ++j) {
        int i = w * 8 + j;
        float gval = GS[i][l];
        cum += gval;
        float e = expf(cum);
        float s_ = 1.f - expf(gval);
        float r_ = s_ / e;
        EB[i][l] = f2us(e);
        RB[i][XS(i, l)] = f2us(r_);
        RT[l][XS(l, i)] = f2us(r_);
      }
    }
    __syncthreads();

    // ---- ph2: stage q,k tiles from regs (GS dead) ----
#pragma unroll
    for (int s = 0; s < 4; ++s) {
      int id = s * 512 + tid, row = id >> 5, cc = (id & 31) * 8;
      int sc = XS(row, cc);
      *(uint4*)&QT[row][sc] = pq[s];
      *(uint4*)&KT[row][sc] = pk[s];
    }
    __syncthreads();

    // issue next chunk's G/Q/K prefetch (hidden under ph3..ph9)
    if (cl + 1 < NCH) { pref_g(c + 1); pref_qk(c + 1); }

    // ---- ph3: S = QK^T (->SB, causal) and o1 += Q Gk^T ----
    f32x4 o1acc[2];
    o1acc[0] = (f32x4){0.f, 0.f, 0.f, 0.f};
    o1acc[1] = (f32x4){0.f, 0.f, 0.f, 0.f};
    {
      f32x4 sacc[2];
      sacc[0] = (f32x4){0.f, 0.f, 0.f, 0.f};
      sacc[1] = (f32x4){0.f, 0.f, 0.f, 0.f};
      int ar_ = wlo * 16 + fr;
#pragma unroll
      for (int kk = 0; kk < 8; ++kk) {
        bf16x8 aq = *(const bf16x8*)&QT[ar_][XS(ar_, kk * 32 + fq * 8)];
#pragma unroll
        for (int t2 = 0; t2 < 2; ++t2) {
          int tj = (whi + 2 * t2) * 16 + fr;
          int bc = XS(tj, kk * 32 + fq * 8);
          bf16x8 bk = *(const bf16x8*)&KT[tj][bc];
          sacc[t2] = __builtin_amdgcn_mfma_f32_16x16x32_bf16(aq, bk, sacc[t2], 0, 0, 0);
          bf16x8 bg = *(const bf16x8*)&GkB[tj][bc];
          o1acc[t2] = __builtin_amdgcn_mfma_f32_16x16x32_bf16(aq, bg, o1acc[t2], 0, 0, 0);
        }
      }
#pragma unroll
      for (int t2 = 0; t2 < 2; ++t2)
#pragma unroll
        for (int rr = 0; rr < 4; ++rr) {
          int i = wlo * 16 + fq * 4 + rr;
          int tau = (whi + 2 * t2) * 16 + fr;
          SB[i][XS(i, tau)] = f2us(tau <= i ? sacc[t2][rr] : 0.f);
        }
    }
    __syncthreads();

    // ---- ph4: o1 += S r (intra); write O1B = e * o1 ----
    {
      int ar_ = wlo * 16 + fr;
#pragma unroll
      for (int kk = 0; kk < 2; ++kk) {
        bf16x8 as = *(const bf16x8*)&SB[ar_][XS(ar_, kk * 32 + fq * 8)];
#pragma unroll
        for (int t2 = 0; t2 < 2; ++t2) {
          int tj = (whi + 2 * t2) * 16 + fr;
          bf16x8 br = *(const bf16x8*)&RT[tj][XS(tj, kk * 32 + fq * 8)];
          o1acc[t2] = __builtin_amdgcn_mfma_f32_16x16x32_bf16(as, br, o1acc[t2], 0, 0, 0);
        }
      }
#pragma unroll
      for (int t2 = 0; t2 < 2; ++t2)
#pragma unroll
        for (int rr = 0; rr < 4; ++rr) {
          int i = wlo * 16 + fq * 4 + rr;
          int m = (whi + 2 * t2) * 16 + fr;
          O1B[i][XS(i, m)] = f2us(u2f(EB[i][m]) * o1acc[t2][rr]);
        }
    }
    __syncthreads();

    // ---- ph5: softmax rows -> u = qv*e (UB);  wT = e63*r^T in place ----
    {
      int i = tid >> 3, mq = tid & 7;
      int sc = XS(i, mq * 8);
      uint4 raw = *(const uint4*)&O1B[i][sc];
      const unsigned short* rp = (const unsigned short*)&raw;
      float x[8];
#pragma unroll
      for (int j = 0; j < 8; ++j) x[j] = u2f(rp[j]);
      float mx = x[0];
#pragma unroll
      for (int j = 1; j < 8; ++j) mx = fmaxf(mx, x[j]);
      mx = fmaxf(mx, __shfl_xor(mx, 1, 64));
      mx = fmaxf(mx, __shfl_xor(mx, 2, 64));
      mx = fmaxf(mx, __shfl_xor(mx, 4, 64));
      float ex[8], sum = 0.f;
#pragma unroll
      for (int j = 0; j < 8; ++j) { ex[j] = expf(x[j] - mx); sum += ex[j]; }
      sum += __shfl_xor(sum, 1, 64);
      sum += __shfl_xor(sum, 2, 64);
      sum += __shfl_xor(sum, 4, 64);
      float inv = 1.f / sum;
      unsigned short up[8];
#pragma unroll
      for (int j = 0; j < 8; ++j)
        up[j] = f2us(ex[j] * inv * u2f(EB[i][mq * 8 + j]));
      *(uint4*)&UB[i][sc] = *(uint4*)up;
    }
    {
      int m2 = tid >> 3, tq = tid & 7;
      int sc = XS(m2, tq * 8);
      float e63 = u2f(EB[63][m2]);
      uint4 raw = *(const uint4*)&RT[m2][sc];
      const unsigned short* rp = (const unsigned short*)&raw;
      unsigned short ow[8];
#pragma unroll
      for (int j = 0; j < 8; ++j) ow[j] = f2us(u2f(rp[j]) * e63);
      *(uint4*)&RT[m2][sc] = *(uint4*)ow;
    }
    __syncthreads();

    // ---- ph6: P^T = r u^T -> SB (transposed write, causal); K->KTt1 ----
    {
      f32x4 pacc[2];
      pacc[0] = (f32x4){0.f, 0.f, 0.f, 0.f};
      pacc[1] = (f32x4){0.f, 0.f, 0.f, 0.f};
      int ar_ = wlo * 16 + fr;
#pragma unroll
      for (int kk = 0; kk < 2; ++kk) {
        bf16x8 ar = *(const bf16x8*)&RB[ar_][XS(ar_, kk * 32 + fq * 8)];
#pragma unroll
        for (int t2 = 0; t2 < 2; ++t2) {
          int tj = (whi + 2 * t2) * 16 + fr;
          bf16x8 bu = *(const bf16x8*)&UB[tj][XS(tj, kk * 32 + fq * 8)];
          pacc[t2] = __builtin_amdgcn_mfma_f32_16x16x32_bf16(ar, bu, pacc[t2], 0, 0, 0);
        }
      }
#pragma unroll
      for (int t2 = 0; t2 < 2; ++t2)
#pragma unroll
        for (int rr = 0; rr < 4; ++rr) {
          int tau = wlo * 16 + fq * 4 + rr;
          int i = (whi + 2 * t2) * 16 + fr;
          SB[i][XS(i, tau)] = f2us(tau <= i ? pacc[t2][rr] : 0.f);  // PB
        }
    }
    if (upd) {
#pragma unroll
      for (int s = 0; s < 2; ++s) {
        int id = s * 512 + tid, d8 = id & 15, tau = id >> 4;
        uint4 raw = *(const uint4*)&KT[tau][XS(tau, d8 * 8)];
        const unsigned short* rp = (const unsigned short*)&raw;
#pragma unroll
        for (int j = 0; j < 8; ++j) {
          int trow = d8 * 8 + j;
          KTt1[trow][XS(trow, tau)] = rp[j];
        }
      }
    }
    __syncthreads();

    // ---- ph7a: waves0-3: Gk update (d<128);  waves4-7: K->KTt2 ----
    if (upd) {
      if (w < 4) {
        float e63r[4];
#pragma unroll
        for (int rr = 0; rr < 4; ++rr) e63r[rr] = u2f(EB[63][wlo * 16 + fq * 4 + rr]);
        int wr = wlo * 16 + fr;
        bf16x8 aw0 = *(const bf16x8*)&RT[wr][XS(wr, fq * 8)];
        bf16x8 aw1 = *(const bf16x8*)&RT[wr][XS(wr, 32 + fq * 8)];
#pragma unroll
        for (int jj = 0; jj < 8; ++jj) {
#pragma unroll
          for (int rr = 0; rr < 4; ++rr) gk[jj][rr] *= e63r[rr];
          int kr = jj * 16 + fr;
          bf16x8 bk0 = *(const bf16x8*)&KTt1[kr][XS(kr, fq * 8)];
          bf16x8 bk1 = *(const bf16x8*)&KTt1[kr][XS(kr, 32 + fq * 8)];
          gk[jj] = __builtin_amdgcn_mfma_f32_16x16x32_bf16(aw0, bk0, gk[jj], 0, 0, 0);
          gk[jj] = __builtin_amdgcn_mfma_f32_16x16x32_bf16(aw1, bk1, gk[jj], 0, 0, 0);
        }
      } else {
#pragma unroll
        for (int s = 0; s < 4; ++s) {
          int id = s * 256 + (tid - 256), d8 = id & 15, tau = id >> 4;
          uint4 raw = *(const uint4*)&KT[tau][XS(tau, 128 + d8 * 8)];
          const unsigned short* rp = (const unsigned short*)&raw;
#pragma unroll
          for (int j = 0; j < 8; ++j) {
            int trow = d8 * 8 + j;
            KTt2[trow][XS(trow, tau)] = rp[j];
          }
        }
      }
    }
    __syncthreads();

    // ---- ph7b: waves4-7: Gk update (d>=128); waves0-3: VTt1 + GvB1 ----
    if (upd && w >= 4) {
      float e63r[4];
#pragma unroll
      for (int rr = 0; rr < 4; ++rr) e63r[rr] = u2f(EB[63][wlo * 16 + fq * 4 + rr]);
      int wr = wlo * 16 + fr;
      bf16x8 aw0 = *(const bf16x8*)&RT[wr][XS(wr, fq * 8)];
      bf16x8 aw1 = *(const bf16x8*)&RT[wr][XS(wr, 32 + fq * 8)];
#pragma unroll
      for (int jj = 0; jj < 8; ++jj) {
#pragma unroll
        for (int rr = 0; rr < 4; ++rr) gk[jj][rr] *= e63r[rr];
        int kr = jj * 16 + fr;
        bf16x8 bk0 = *(const bf16x8*)&KTt2[kr][XS(kr, fq * 8)];
        bf16x8 bk1 = *(const bf16x8*)&KTt2[kr][XS(kr, 32 + fq * 8)];
        gk[jj] = __builtin_amdgcn_mfma_f32_16x16x32_bf16(aw0, bk0, gk[jj], 0, 0, 0);
        gk[jj] = __builtin_amdgcn_mfma_f32_16x16x32_bf16(aw1, bk1, gk[jj], 0, 0, 0);
      }
    }
    if (w < 4) {
#pragma unroll
      for (int s = 0; s < 4; ++s) {
        int id = s * 256 + tid, u8 = id & 15, tau = id >> 4;
        const unsigned short* rp = (const unsigned short*)&pv1[s];
#pragma unroll
        for (int j = 0; j < 8; ++j) {
          int trow = u8 * 8 + j;
          VTt1[trow][XS(trow, tau)] = rp[j];
        }
      }
#pragma unroll
      for (int jj = 0; jj < 8; ++jj) {
        int u0 = (wlo * 2 + (jj >> 2)) * 16 + fq * 4;
        int m = (jj & 3) * 16 + fr;
#pragma unroll
        for (int rr = 0; rr < 4; ++rr) {
          int grow = u0 + rr;
          GvB1[grow][XS(grow, m)] = f2us(gv[jj][rr]);
        }
      }
    }
    __syncthreads();

    // ---- ph8: o(u<128) -> O ; w<4: Gv upd h1; VTt2 stage; w>=4: GvB2 ----
    {
      int pr = wlo * 16 + fr;
      bf16x8 ap0 = *(const bf16x8*)&SB[pr][XS(pr, fq * 8)];
      bf16x8 ap1 = *(const bf16x8*)&SB[pr][XS(pr, 32 + fq * 8)];
      bf16x8 au0 = *(const bf16x8*)&UB[pr][XS(pr, fq * 8)];
      bf16x8 au1 = *(const bf16x8*)&UB[pr][XS(pr, 32 + fq * 8)];
#pragma unroll
      for (int oo = 0; oo < 4; ++oo) {
        int ut = whi * 4 + oo;
        int vr = ut * 16 + fr;
        f32x4 oa = (f32x4){0.f, 0.f, 0.f, 0.f};
        bf16x8 bv0 = *(const bf16x8*)&VTt1[vr][XS(vr, fq * 8)];
        bf16x8 bv1 = *(const bf16x8*)&VTt1[vr][XS(vr, 32 + fq * 8)];
        bf16x8 bg0 = *(const bf16x8*)&GvB1[vr][XS(vr, fq * 8)];
        bf16x8 bg1 = *(const bf16x8*)&GvB1[vr][XS(vr, 32 + fq * 8)];
        oa = __builtin_amdgcn_mfma_f32_16x16x32_bf16(ap0, bv0, oa, 0, 0, 0);
        oa = __builtin_amdgcn_mfma_f32_16x16x32_bf16(ap1, bv1, oa, 0, 0, 0);
        oa = __builtin_amdgcn_mfma_f32_16x16x32_bf16(au0, bg0, oa, 0, 0, 0);
        oa = __builtin_amdgcn_mfma_f32_16x16x32_bf16(au1, bg1, oa, 0, 0, 0);
#pragma unroll
        for (int rr = 0; rr < 4; ++rr)
          O[(size_t)(rowbase + wlo * 16 + fq * 4 + rr) * 2048 + h * 256 + ut * 16 + fr] = oa[rr];
      }
    }
#pragma unroll
    for (int s = 0; s < 2; ++s) {
      int id = s * 512 + tid, u8 = id & 15, tau = id >> 4;
      const unsigned short* rp = (const unsigned short*)&pv2[s];
#pragma unroll
      for (int j = 0; j < 8; ++j) {
        int trow = u8 * 8 + j;
        VTt2[trow][XS(trow, tau)] = rp[j];
      }
    }
    // V regs free -> issue next chunk's V prefetch (hidden under ph9+ph1..7)
    if (cl + 1 < NCH) pref_v(c + 1);
    if (w < 4) {
      if (upd) {
#pragma unroll
        for (int jj = 0; jj < 8; ++jj) {
          int ut = wlo * 2 + (jj >> 2), mt = jj & 3;
          float e63v = u2f(EB[63][mt * 16 + fr]);
#pragma unroll
          for (int rr = 0; rr < 4; ++rr) gv[jj][rr] *= e63v;
          int vr = ut * 16 + fr, br_ = mt * 16 + fr;
          bf16x8 av0 = *(const bf16x8*)&VTt1[vr][XS(vr, fq * 8)];
          bf16x8 av1 = *(const bf16x8*)&VTt1[vr][XS(vr, 32 + fq * 8)];
          bf16x8 bw0 = *(const bf16x8*)&RT[br_][XS(br_, fq * 8)];
          bf16x8 bw1 = *(const bf16x8*)&RT[br_][XS(br_, 32 + fq * 8)];
          gv[jj] = __builtin_amdgcn_mfma_f32_16x16x32_bf16(av0, bw0, gv[jj], 0, 0, 0);
          gv[jj] = __builtin_amdgcn_mfma_f32_16x16x32_bf16(av1, bw1, gv[jj], 0, 0, 0);
        }
      }
    } else {
#pragma unroll
      for (int jj = 0; jj < 8; ++jj) {
        int u0 = (wlo * 2 + (jj >> 2)) * 16 + fq * 4;
        int m = (jj & 3) * 16 + fr;
#pragma unroll
        for (int rr = 0; rr < 4; ++rr) {
          int grow = u0 + rr;
          GvB2[grow][XS(grow, m)] = f2us(gv[jj][rr]);
        }
      }
    }
    __syncthreads();

    // ---- ph9: o(u>=128) -> O ; waves4-7: Gv upd h2 ----
    {
      int pr = wlo * 16 + fr;
      bf16x8 ap0 = *(const bf16x8*)&SB[pr][XS(pr, fq * 8)];
      bf16x8 ap1 = *(const bf16x8*)&SB[pr][XS(pr, 32 + fq * 8)];
      bf16x8 au0 = *(const bf16x8*)&UB[pr][XS(pr, fq * 8)];
      bf16x8 au1 = *(const bf16x8*)&UB[pr][XS(pr, 32 + fq * 8)];
#pragma unroll
      for (int oo = 0; oo < 4; ++oo) {
        int utl = whi * 4 + oo;  // local u-tile (global ut = 8+utl)
        int vr = utl * 16 + fr;
        f32x4 oa = (f32x4){0.f, 0.f, 0.f, 0.f};
        bf16x8 bv0 = *(const bf16x8*)&VTt2[vr][XS(vr, fq * 8)];
        bf16x8 bv1 = *(const bf16x8*)&VTt2[vr][XS(vr, 32 + fq * 8)];
        bf16x8 bg0 = *(const bf16x8*)&GvB2[vr][XS(vr, fq * 8)];
        bf16x8 bg1 = *(const bf16x8*)&GvB2[vr][XS(vr, 32 + fq * 8)];
        oa = __builtin_amdgcn_mfma_f32_16x16x32_bf16(ap0, bv0, oa, 0, 0, 0);
        oa = __builtin_amdgcn_mfma_f32_16x16x32_bf16(ap1, bv1, oa, 0, 0, 0);
        oa = __builtin_amdgcn_mfma_f32_16x16x32_bf16(au0, bg0, oa, 0, 0, 0);
        oa = __builtin_amdgcn_mfma_f32_16x16x32_bf16(au1, bg1, oa, 0, 0, 0);
#pragma unroll
        for (int rr = 0; rr < 4; ++rr)
          O[(size_t)(rowbase + wlo * 16 + fq * 4 + rr) * 2048 + h * 256 + 128 + utl * 16 + fr] = oa[rr];
      }
    }
    if (upd && w >= 4) {
#pragma unroll
      for (int jj = 0; jj < 8; ++jj) {
        int utl = wlo * 2 + (jj >> 2), mt = jj & 3;
        float e63v = u2f(EB[63][mt * 16 + fr]);
#pragma unroll
        for (int rr = 0; rr < 4; ++rr) gv[jj][rr] *= e63v;
        int vr = utl * 16 + fr, br_ = mt * 16 + fr;
        bf16x8 av0 = *(const bf16x8*)&VTt2[vr][XS(vr, fq * 8)];
        bf16x8 av1 = *(const bf16x8*)&VTt2[vr][XS(vr, 32 + fq * 8)];
        bf16x8 bw0 = *(const bf16x8*)&RT[br_][XS(br_, fq * 8)];
        bf16x8 bw1 = *(const bf16x8*)&RT[br_][XS(br_, 32 + fq * 8)];
        gv[jj] = __builtin_amdgcn_mfma_f32_16x16x32_bf16(av0, bw0, gv[jj], 0, 0, 0);
        gv[jj] = __builtin_amdgcn_mfma_f32_16x16x32_bf16(av1, bw1, gv[jj], 0, 0, 0);
      }
    }
    __syncthreads();
  }
}

// --------------------------------------------- Phase A: segment deltas ---
__global__ __launch_bounds__(512, 1) void gsa_segA_kernel(
    const unsigned short* __restrict__ K, const unsigned short* __restrict__ V,
    const float* __restrict__ G, float* __restrict__ DK, float* __restrict__ DV,
    float* __restrict__ ES)
{
  __shared__ __align__(16) char pool[135552];
  float (*GS)[64] = (float(*)[64])(pool);             // 16384
  float (*red)[68] = (float(*)[68])(pool + 16384);    // 2176
  auto RT   = (unsigned short(*)[72])(pool + 18560);  // 9216
  float* e63f = (float*)(pool + 27776);               // 256
  auto KT   = (unsigned short(*)[264])(pool + 28032); // 33792
  auto KTt1 = (unsigned short(*)[72])(pool + 61824);  // 18432
  auto KTt2 = (unsigned short(*)[72])(pool + 80256);
  auto VTt1 = (unsigned short(*)[72])(pool + 98688);
  auto VTt2 = (unsigned short(*)[72])(pool + 117120); // end 135552

  const int bh = (int)blockIdx.x >> 3, seg = (int)blockIdx.x & 7;
  const int b = bh >> 3, h = bh & 7;
  const int tid = threadIdx.x;
  const int w = tid >> 6, l = tid & 63, fr = l & 15, fq = l >> 4;
  const int wlo = w & 3, whi = w >> 2;

  // ---- prefetch registers ----
  float4 pg[2];
  uint4 pk[4], pv[4];
  auto pref_gk = [&](int cl) {
    const int rb = b * 2048 + (seg * 4 + cl) * 64;
#pragma unroll
    for (int s = 0; s < 2; ++s) {
      int id = s * 512 + tid, row = id >> 4, mq = id & 15;
      pg[s] = *(const float4*)&G[(size_t)(rb + row) * 512 + h * 64 + mq * 4];
    }
#pragma unroll
    for (int s = 0; s < 4; ++s) {
      int id = s * 512 + tid, row = id >> 5, cc = (id & 31) * 8;
      pk[s] = *(const uint4*)(K + (size_t)(rb + row) * 2048 + h * 256 + cc);
    }
  };
  auto pref_v = [&](int cl) {
    const int rb = b * 2048 + (seg * 4 + cl) * 64;
#pragma unroll
    for (int s = 0; s < 2; ++s) {
      int id = s * 512 + tid, u8 = id & 15, tau = id >> 4;
      size_t gb = (size_t)(rb + tau) * 2048 + h * 256 + u8 * 8;
      pv[s * 2]     = *(const uint4*)(V + gb);
      pv[s * 2 + 1] = *(const uint4*)(V + gb + 128);
    }
  };
  pref_gk(0);
  pref_v(0);

  f32x4 gk[8], gv[8];
#pragma unroll
  for (int jj = 0; jj < 8; ++jj) {
    gk[jj] = (f32x4){0.f, 0.f, 0.f, 0.f};
    gv[jj] = (f32x4){0.f, 0.f, 0.f, 0.f};
  }
  float gsum = 0.f;  // valid on w==7 threads

  for (int cl = 0; cl < 4; ++cl) {
    // ph1: stage G + K from regs
#pragma unroll
    for (int s = 0; s < 2; ++s) {
      int id = s * 512 + tid, row = id >> 4, mq = id & 15;
      *(float4*)&GS[row][mq * 4] = pg[s];
    }
#pragma unroll
    for (int s = 0; s < 4; ++s) {
      int id = s * 512 + tid, row = id >> 5, cc = (id & 31) * 8;
      *(uint4*)&KT[row][XS(row, cc)] = pk[s];
    }
    __syncthreads();

    // issue next chunk's G/K prefetch (hidden under ph2..ph5)
    if (cl + 1 < 4) pref_gk(cl + 1);

    // ph2: prefix partials
    {
      float ps = 0.f;
#pragma unroll
      for (int j = 0; j < 8; ++j) ps += GS[w * 8 + j][l];
      red[w][l] = ps;
    }
    __syncthreads();

    // ph3: cum -> RT (r^T), e63, segment g-sum
    {
      float cum = 0.f;
      for (int g2 = 0; g2 < w; ++g2) cum += red[g2][l];
#pragma unroll
      for (int j = 0; j < 8; ++j) {
        int i = w * 8 + j;
        float gval = GS[i][l];
        cum += gval;
        float e = expf(cum);
        float r_ = (1.f - expf(gval)) / e;
        RT[l][XS(l, i)] = f2us(r_);
      }
      if (w == 7) { gsum += cum; e63f[l] = expf(cum); }
    }
    __syncthreads();

    // ph4: RT *= e63 (-> w^T); K transposes; V transposes (from regs)
    {
      int m2 = tid >> 3, tq = tid & 7;
      int sc = XS(m2, tq * 8);
      float e63 = e63f[m2];
      uint4 raw = *(const uint4*)&RT[m2][sc];
      const unsigned short* rp = (const unsigned short*)&raw;
      unsigned short ow[8];
#pragma unroll
      for (int j = 0; j < 8; ++j) ow[j] = f2us(u2f(rp[j]) * e63);
      *(uint4*)&RT[m2][sc] = *(uint4*)ow;
    }
#pragma unroll
    for (int s = 0; s < 2; ++s) {
      int id = s * 512 + tid, d8 = id & 15, tau = id >> 4;
      uint4 raw1 = *(const uint4*)&KT[tau][XS(tau, d8 * 8)];
      uint4 raw2 = *(const uint4*)&KT[tau][XS(tau, 128 + d8 * 8)];
      const unsigned short* rp1 = (const unsigned short*)&raw1;
      const unsigned short* rp2 = (const unsigned short*)&raw2;
#pragma unroll
      for (int j = 0; j < 8; ++j) {
        int trow = d8 * 8 + j;
        KTt1[trow][XS(trow, tau)] = rp1[j];
        KTt2[trow][XS(trow, tau)] = rp2[j];
      }
    }
#pragma unroll
    for (int s = 0; s < 2; ++s) {
      int id = s * 512 + tid, u8 = id & 15, tau = id >> 4;
      const unsigned short* rp1 = (const unsigned short*)&pv[s * 2];
      const unsigned short* rp2 = (const unsigned short*)&pv[s * 2 + 1];
#pragma unroll
      for (int j = 0; j < 8; ++j) {
        int trow = u8 * 8 + j;
        VTt1[trow][XS(trow, tau)] = rp1[j];
        VTt2[trow][XS(trow, tau)] = rp2[j];
      }
    }
    // V regs free -> issue next chunk's V prefetch
    if (cl + 1 < 4) pref_v(cl + 1);
    __syncthreads();

    // ph5: gk += w^T K ; gv += V^T w
    {
      float e63r[4];
#pragma unroll
      for (int rr = 0; rr < 4; ++rr) e63r[rr] = e63f[wlo * 16 + fq * 4 + rr];
      int wr = wlo * 16 + fr;
      bf16x8 aw0 = *(const bf16x8*)&RT[wr][XS(wr, fq * 8)];
      bf16x8 aw1 = *(const bf16x8*)&RT[wr][XS(wr, 32 + fq * 8)];
      auto KTx = (w < 4) ? KTt1 : KTt2;
#pragma unroll
      for (int jj = 0; jj < 8; ++jj) {
#pragma unroll
        for (int rr = 0; rr < 4; ++rr) gk[jj][rr] *= e63r[rr];
        int kr = jj * 16 + fr;
        bf16x8 bk0 = *(const bf16x8*)&KTx[kr][XS(kr, fq * 8)];
        bf16x8 bk1 = *(const bf16x8*)&KTx[kr][XS(kr, 32 + fq * 8)];
        gk[jj] = __builtin_amdgcn_mfma_f32_16x16x32_bf16(aw0, bk0, gk[jj], 0, 0, 0);
        gk[jj] = __builtin_amdgcn_mfma_f32_16x16x32_bf16(aw1, bk1, gk[jj], 0, 0, 0);
      }
      auto VTx = (w < 4) ? VTt1 : VTt2;
#pragma unroll
      for (int jj = 0; jj < 8; ++jj) {
        int utl = wlo * 2 + (jj >> 2), mt = jj & 3;
        float e63v = e63f[mt * 16 + fr];
#pragma unroll
        for (int rr = 0; rr < 4; ++rr) gv[jj][rr] *= e63v;
        int vr = utl * 16 + fr, br_ = mt * 16 + fr;
        bf16x8 av0 = *(const bf16x8*)&VTx[vr][XS(vr, fq * 8)];
        bf16x8 av1 = *(const bf16x8*)&VTx[vr][XS(vr, 32 + fq * 8)];
        bf16x8 bw0 = *(const bf16x8*)&RT[br_][XS(br_, fq * 8)];
        bf16x8 bw1 = *(const bf16x8*)&RT[br_][XS(br_, 32 + fq * 8)];
        gv[jj] = __builtin_amdgcn_mfma_f32_16x16x32_bf16(av0, bw0, gv[jj], 0, 0, 0);
        gv[jj] = __builtin_amdgcn_mfma_f32_16x16x32_bf16(av1, bw1, gv[jj], 0, 0, 0);
      }
    }
    __syncthreads();
  }

  // write deltas + segment decay
  float* dk = DK + ((size_t)bh * 8 + seg) * 16384;
  float* dv = DV + ((size_t)bh * 8 + seg) * 16384;
#pragma unroll
  for (int jj = 0; jj < 8; ++jj) {
    int ut = (w >= 4 ? 8 : 0) + wlo * 2 + (jj >> 2);
#pragma unroll
    for (int rr = 0; rr < 4; ++rr) {
      dk[(wlo * 16 + fq * 4 + rr) * 256 + (whi * 8 + jj) * 16 + fr] = gk[jj][rr];
      dv[(ut * 16 + fq * 4 + rr) * 64 + (jj & 3) * 16 + fr] = gv[jj][rr];
    }
  }
  if (w == 7) ES[((size_t)bh * 8 + seg) * 64 + l] = expf(gsum);
}

// ------------------------------------------- Phase B: prefix combine ---
__global__ __launch_bounds__(1024) void gsa_segB_kernel(
    float* __restrict__ DK, float* __restrict__ DV, const float* __restrict__ ES)
{
  const int bh = blockIdx.x, tid = threadIdx.x;
  __shared__ float es[8][64];
  if (tid < 512) es[tid >> 6][tid & 63] = ES[(size_t)bh * 512 + tid];
  __syncthreads();
  float* dk = DK + (size_t)bh * 8 * 16384;
  float* dv = DV + (size_t)bh * 8 * 16384;
  for (int k = 0; k < 16; ++k) {
    int e = k * 1024 + tid;
    int m = e >> 8;                 // DK: e = m*256 + d
    float S = 0.f;
#pragma unroll
    for (int s = 0; s < 8; ++s) {
      float d = dk[s * 16384 + e];
      dk[s * 16384 + e] = S;
      S = fmaf(S, es[s][m], d);
    }
  }
  for (int k = 0; k < 16; ++k) {
    int e = k * 1024 + tid;
    int m = e & 63;                 // DV: e = u*64 + m
    float S = 0.f;
#pragma unroll
    for (int s = 0; s < 8; ++s) {
      float d = dv[s * 16384 + e];
      dv[s * 16384 + e] = S;
      S = fmaf(S, es[s][m], d);
    }
  }
}

// ------------------------------------------------------------- sentinel ---
__global__ __launch_bounds__(256) void fillf_kernel(float* o, float v) {
  o[(size_t)blockIdx.x * 256 + threadIdx.x] = v;
}

// --------------------------------------------------------------- launch ---
extern "C" void kernel_launch(void* const* d_in, const int* in_sizes, int n_in,
                              void* d_out, int out_size, void* d_ws, size_t ws_size,
                              hipStream_t stream)
{
  const float* hidden   = (const float*)d_in[0];
  const float* norm_w   = (const float*)d_in[1];
  const float* q_w      = (const float*)d_in[2];
  const float* k_w      = (const float*)d_in[3];
  const float* v_w      = (const float*)d_in[4];
  const float* f_w      = (const float*)d_in[5];
  const float* g_norm_w = (const float*)d_in[6];
  const float* o_w      = (const float*)d_in[7];

  float* dout = (float*)d_out;
  char* ws = (char*)d_ws;
  const size_t SZB = (size_t)ROWS * DM * 2;        // 32MiB bf16 activation
  const size_t SZG = (size_t)ROWS * 512 * 4;       // 16MiB f32 gates
  const size_t NEED = 4 * SZB + SZG;               // 144MiB
  const size_t SZD = (size_t)32 * 8 * 16384 * 4;   // 16MiB per delta array
  const size_t NEED_BIG = NEED + 2 * SZD + (size_t)32 * 8 * 64 * 4;
  const size_t SZWB = (size_t)DM * DM * 2;         // 8MiB bf16 weight
  const size_t SZWF = (size_t)512 * DM * 2;        // 2MiB bf16 f-weight
  const size_t NEED_W = NEED_BIG + 4 * SZWB + SZWF;

  if (ws_size < NEED) {
    fillf_kernel<<<65536, 256, 0, stream>>>(dout, 123.0f);
    return;
  }

  unsigned short* XN = (unsigned short*)(ws);      // xnorm, later o_act
  unsigned short* Qb = (unsigned short*)(ws + SZB);
  unsigned short* Kb = (unsigned short*)(ws + 2 * SZB);
  unsigned short* Vb = (unsigned short*)(ws + 3 * SZB);
  float* Gb          = (float*)(ws + 4 * SZB);
  float* DK          = (float*)(ws + NEED);
  float* DV          = DK + (size_t)32 * 8 * 16384;
  float* ES          = DV + (size_t)32 * 8 * 16384;
  unsigned short* WQ = (unsigned short*)(ws + NEED_BIG);
  unsigned short* WK = WQ + SZWB / 2;
  unsigned short* WV = WK + SZWB / 2;
  unsigned short* WO = WV + SZWB / 2;
  unsigned short* WF = WO + SZWB / 2;

  xnorm_kernel<<<ROWS, 256, 0, stream>>>(hidden, norm_w, XN);

  if (ws_size >= NEED_W) {
    // weight pre-conversion (f32 -> bf16, RNE; same rounding as before)
    wconv_kernel<<<2048, 256, 0, stream>>>(q_w, WQ);
    wconv_kernel<<<2048, 256, 0, stream>>>(k_w, WK);
    wconv_kernel<<<2048, 256, 0, stream>>>(v_w, WV);
    wconv_kernel<<<2048, 256, 0, stream>>>(o_w, WO);
    wconv_kernel<<<512, 256, 0, stream>>>(f_w, WF);

    mgemm2_kernel<<<dim3(16, 64), 256, 0, stream>>>(XN, WQ, Qb, nullptr, 2048, MODE_SWISH);
    mgemm2_kernel<<<dim3(16, 64), 256, 0, stream>>>(XN, WK, Kb, nullptr, 2048, MODE_SWISH);
    mgemm2_kernel<<<dim3(16, 64), 256, 0, stream>>>(XN, WV, Vb, nullptr, 2048, MODE_SWISH);
    mgemm2_kernel<<<dim3(4, 64), 256, 0, stream>>>(XN, WF, nullptr, Gb, 512, MODE_GATE);
  } else {
    mgemm_kernel<<<dim3(16, 64), 256, 0, stream>>>(XN, q_w, Qb, nullptr, 2048, MODE_SWISH);
    mgemm_kernel<<<dim3(16, 64), 256, 0, stream>>>(XN, k_w, Kb, nullptr, 2048, MODE_SWISH);
    mgemm_kernel<<<dim3(16, 64), 256, 0, stream>>>(XN, v_w, Vb, nullptr, 2048, MODE_SWISH);
    mgemm_kernel<<<dim3(4, 64), 256, 0, stream>>>(XN, f_w, nullptr, Gb, 512, MODE_GATE);
  }

  if (ws_size >= NEED_BIG) {
    gsa_segA_kernel<<<256, 512, 0, stream>>>(Kb, Vb, Gb, DK, DV, ES);
    gsa_segB_kernel<<<32, 1024, 0, stream>>>(DK, DV, ES);
    gsa_chunk_t<4, true><<<256, 512, 0, stream>>>(Qb, Kb, Vb, Gb, dout, DK, DV);
  } else {
    gsa_chunk_t<32, false><<<32, 512, 0, stream>>>(Qb, Kb, Vb, Gb, dout, nullptr, nullptr);
  }

  oact_norm_kernel<<<ROWS, 256, 0, stream>>>(dout, g_norm_w, XN);

  if (ws_size >= NEED_W)
    mgemm2_kernel<<<dim3(16, 64), 256, 0, stream>>>(XN, WO, nullptr, dout, 2048, MODE_F32);
  else
    mgemm_kernel<<<dim3(16, 64), 256, 0, stream>>>(XN, o_w, nullptr, dout, 2048, MODE_F32);
}

// Round 7
// 851.557 us; speedup vs baseline: 1.2038x; 1.2038x over previous
//
#include <hip/hip_runtime.h>
#include <hip/hip_bf16.h>
#include <math.h>

// Gated Slot Attention. Inputs f32, output f32.
// ROUND 15:
//  - REVERT scan prefetch (R13/R14): 128-VGPR cap is immovable
//    (launch_bounds(512,1) was a byte-identical no-op), prefetch state
//    always spills (+93MB scratch, scan 152->200us). Scan kernels are
//    back to the R4-proven form (152us, WRITE 107MB).
//  - FUSE Q/K/V/F projection GEMMs into ONE dispatch over concatenated
//    weights (N=6656, grid 52x64, bijective XCD swizzle): removes 3
//    launch tails, interleaves A-panel reads in one L2 window.
//  - mgemm2 (with XCD swizzle, proven R5/R6) kept for O-projection.

typedef __bf16 bf16x8 __attribute__((ext_vector_type(8)));
typedef float f32x4 __attribute__((ext_vector_type(4)));

#define ROWS 8192   // B*T
#define DM 2048

#define MODE_F32 0
#define MODE_SWISH 1
#define MODE_GATE 2

// LDS bank-conflict swizzle for the scan buffers (stride 72/264 shorts).
#define XS(r, c) ((c) ^ ((r) & 56))

__device__ __forceinline__ float u2f(unsigned short u) {
  union { unsigned int i; float f; } cv; cv.i = ((unsigned int)u) << 16; return cv.f;
}
__device__ __forceinline__ unsigned short f2us(float f) {
  return __builtin_bit_cast(unsigned short, __float2bfloat16(f));
}
__device__ __forceinline__ float swishf(float v) { return v / (1.f + expf(-v)); }

// async global->LDS, 16B per lane; LDS dest = wave-uniform base + lane*16.
__device__ __forceinline__ void gload16(const void* g, void* l) {
  __builtin_amdgcn_global_load_lds(
      (const __attribute__((address_space(1))) void*)g,
      (__attribute__((address_space(3))) void*)l, 16, 0, 0);
}

// --------------------------------------------------------------- xnorm ---
__global__ __launch_bounds__(256) void xnorm_kernel(
    const float* __restrict__ in, const float* __restrict__ w,
    unsigned short* __restrict__ out)
{
  const int row = blockIdx.x, tid = threadIdx.x;
  const size_t base = (size_t)row * DM + tid * 8;
  float a[8];
#pragma unroll
  for (int i = 0; i < 8; ++i) a[i] = in[base + i];
  float ss = 0.f;
#pragma unroll
  for (int i = 0; i < 8; ++i) ss += a[i] * a[i];
#pragma unroll
  for (int off = 32; off; off >>= 1) ss += __shfl_xor(ss, off, 64);
  __shared__ float wsum[4];
  if ((tid & 63) == 0) wsum[tid >> 6] = ss;
  __syncthreads();
  float tot = wsum[0] + wsum[1] + wsum[2] + wsum[3];
  float rstd = rsqrtf(tot * (1.f / (float)DM) + 1e-5f);
#pragma unroll
  for (int i = 0; i < 8; ++i)
    out[base + i] = f2us(a[i] * rstd * w[tid * 8 + i]);
}

// ---------------------------------------------------------- oact_norm ---
__global__ __launch_bounds__(256) void oact_norm_kernel(
    const float* __restrict__ o, const float* __restrict__ w,
    unsigned short* __restrict__ out)
{
  const int row = blockIdx.x, tid = threadIdx.x;
  const size_t base = (size_t)row * DM + tid * 8;
  float a[8];
#pragma unroll
  for (int i = 0; i < 8; ++i) a[i] = swishf(o[base + i]);
  float ss = 0.f;
#pragma unroll
  for (int i = 0; i < 8; ++i) ss += a[i] * a[i];
#pragma unroll
  for (int off = 32; off; off >>= 1) ss += __shfl_xor(ss, off, 64);
  __shared__ float wsum[4];
  if ((tid & 63) == 0) wsum[tid >> 6] = ss;
  __syncthreads();
  float tot = wsum[0] + wsum[1] + wsum[2] + wsum[3];
  float rstd = rsqrtf(tot * (1.f / (float)DM) + 1e-5f);
#pragma unroll
  for (int i = 0; i < 8; ++i)
    out[base + i] = f2us(a[i] * rstd * w[tid * 8 + i]);
}

// -------------------------------------------------- weight f32->bf16 ---
__global__ __launch_bounds__(256) void wconv_kernel(
    const float* __restrict__ in, unsigned short* __restrict__ out)
{
  size_t i = ((size_t)blockIdx.x * 256 + threadIdx.x) * 8;
  float4 a = *(const float4*)(in + i);
  float4 b = *(const float4*)(in + i + 4);
  unsigned short u[8] = {f2us(a.x), f2us(a.y), f2us(a.z), f2us(a.w),
                         f2us(b.x), f2us(b.y), f2us(b.z), f2us(b.w)};
  *(uint4*)(out + i) = *(const uint4*)u;
}

// ------------------------------------------- MFMA GEMM v2 (glds) ---
// C[m,n] = epilogue( sum_k A[m,k]*WB[n,k] ); A,WB bf16 row-major K=2048.
// 128x128 tile, BK=32, 2x2 waves of 64x64, 16x16x32 bf16 MFMA.
// LDS tile linear (glds dest); chunk swizzle cb^=(row>>1)&3 applied on
// the GLOBAL source and on reads. XCD chunk swizzle on blockIdx.
__global__ __launch_bounds__(256) void mgemm2_kernel(
    const unsigned short* __restrict__ A, const unsigned short* __restrict__ WB,
    unsigned short* __restrict__ outB, float* __restrict__ outF,
    int N, int mode)
{
  __shared__ __align__(16) unsigned short As[128 * 32];
  __shared__ __align__(16) unsigned short Bs[128 * 32];
  const int tid = threadIdx.x;
  // XCD chunk swizzle: nwg divisible by 8 -> bijective.
  const int bid = (int)(blockIdx.y * gridDim.x + blockIdx.x);
  const int nwg = (int)(gridDim.x * gridDim.y);
  const int cpx = nwg >> 3;
  const int swz = (bid & 7) * cpx + (bid >> 3);
  const int bn = swz % (int)gridDim.x, bm = swz / (int)gridDim.x;
  const int w = tid >> 6, l = tid & 63;
  const int wm = w & 1, wn = w >> 1;
  const int fr = l & 15, fq = l >> 4;

  f32x4 acc[4][4];
#pragma unroll
  for (int i = 0; i < 4; ++i)
#pragma unroll
    for (int j = 0; j < 4; ++j) acc[i][j] = (f32x4){0.f, 0.f, 0.f, 0.f};

  // staging geometry: physical chunk p = w*128 + j*64 + l
  int prow[2], pcol[2];
#pragma unroll
  for (int j = 0; j < 2; ++j) {
    int p = w * 128 + j * 64 + l;
    prow[j] = p >> 2;
    pcol[j] = ((p & 3) ^ ((prow[j] >> 1) & 3)) * 8;  // element offset in row
  }
  const size_t abase = (size_t)(bm * 128) * DM;
  const size_t bbase = (size_t)(bn * 128) * DM;

  for (int k0 = 0; k0 < DM; k0 += 32) {
#pragma unroll
    for (int j = 0; j < 2; ++j) {
      gload16(A + abase + (size_t)prow[j] * DM + k0 + pcol[j],
              &As[(w * 128 + j * 64) * 8]);
      gload16(WB + bbase + (size_t)prow[j] * DM + k0 + pcol[j],
              &Bs[(w * 128 + j * 64) * 8]);
    }
    __syncthreads();
    bf16x8 af[4], bfr[4];
#pragma unroll
    for (int i = 0; i < 4; ++i) {
      int row = wm * 64 + i * 16 + fr;
      af[i] = *(const bf16x8*)&As[row * 32 + ((fq ^ ((row >> 1) & 3)) * 8)];
    }
#pragma unroll
    for (int j = 0; j < 4; ++j) {
      int row = wn * 64 + j * 16 + fr;
      bfr[j] = *(const bf16x8*)&Bs[row * 32 + ((fq ^ ((row >> 1) & 3)) * 8)];
    }
#pragma unroll
    for (int i = 0; i < 4; ++i)
#pragma unroll
      for (int j = 0; j < 4; ++j)
        acc[i][j] = __builtin_amdgcn_mfma_f32_16x16x32_bf16(af[i], bfr[j], acc[i][j], 0, 0, 0);
    __syncthreads();
  }

#pragma unroll
  for (int i = 0; i < 4; ++i) {
#pragma unroll
    for (int rr = 0; rr < 4; ++rr) {
      int row = bm * 128 + wm * 64 + i * 16 + fq * 4 + rr;
#pragma unroll
      for (int j = 0; j < 4; ++j) {
        int col = bn * 128 + wn * 64 + j * 16 + fr;
        float val = acc[i][j][rr];
        size_t idx = (size_t)row * N + col;
        if (mode == MODE_SWISH)      outB[idx] = f2us(swishf(val));
        else if (mode == MODE_F32)   outF[idx] = val;
        else {  // MODE_GATE
          float ls = fminf(val, 0.f) - log1pf(expf(-fabsf(val)));
          outF[idx] = ls * 0.125f;
        }
      }
    }
  }
}

// -------------------------------- fused Q/K/V/F projection GEMM ---
// WALL = [WQ;WK;WV;WF] bf16 [6656][2048]. Grid 52x64 (nwg=3328, %8==0).
// bn in [0,16)->Qb swish; [16,32)->Kb; [32,48)->Vb; [48,52)->Gb gate.
__global__ __launch_bounds__(256) void mgemm2_fused_kernel(
    const unsigned short* __restrict__ A, const unsigned short* __restrict__ WALL,
    unsigned short* __restrict__ Qb, unsigned short* __restrict__ Kb,
    unsigned short* __restrict__ Vb, float* __restrict__ Gb)
{
  __shared__ __align__(16) unsigned short As[128 * 32];
  __shared__ __align__(16) unsigned short Bs[128 * 32];
  const int tid = threadIdx.x;
  const int bid = (int)(blockIdx.y * gridDim.x + blockIdx.x);
  const int nwg = (int)(gridDim.x * gridDim.y);
  const int cpx = nwg >> 3;
  const int swz = (bid & 7) * cpx + (bid >> 3);
  const int bn = swz % (int)gridDim.x, bm = swz / (int)gridDim.x;
  const int w = tid >> 6, l = tid & 63;
  const int wm = w & 1, wn = w >> 1;
  const int fr = l & 15, fq = l >> 4;

  f32x4 acc[4][4];
#pragma unroll
  for (int i = 0; i < 4; ++i)
#pragma unroll
    for (int j = 0; j < 4; ++j) acc[i][j] = (f32x4){0.f, 0.f, 0.f, 0.f};

  int prow[2], pcol[2];
#pragma unroll
  for (int j = 0; j < 2; ++j) {
    int p = w * 128 + j * 64 + l;
    prow[j] = p >> 2;
    pcol[j] = ((p & 3) ^ ((prow[j] >> 1) & 3)) * 8;
  }
  const size_t abase = (size_t)(bm * 128) * DM;
  const size_t bbase = (size_t)(bn * 128) * DM;

  for (int k0 = 0; k0 < DM; k0 += 32) {
#pragma unroll
    for (int j = 0; j < 2; ++j) {
      gload16(A + abase + (size_t)prow[j] * DM + k0 + pcol[j],
              &As[(w * 128 + j * 64) * 8]);
      gload16(WALL + bbase + (size_t)prow[j] * DM + k0 + pcol[j],
              &Bs[(w * 128 + j * 64) * 8]);
    }
    __syncthreads();
    bf16x8 af[4], bfr[4];
#pragma unroll
    for (int i = 0; i < 4; ++i) {
      int row = wm * 64 + i * 16 + fr;
      af[i] = *(const bf16x8*)&As[row * 32 + ((fq ^ ((row >> 1) & 3)) * 8)];
    }
#pragma unroll
    for (int j = 0; j < 4; ++j) {
      int row = wn * 64 + j * 16 + fr;
      bfr[j] = *(const bf16x8*)&Bs[row * 32 + ((fq ^ ((row >> 1) & 3)) * 8)];
    }
#pragma unroll
    for (int i = 0; i < 4; ++i)
#pragma unroll
      for (int j = 0; j < 4; ++j)
        acc[i][j] = __builtin_amdgcn_mfma_f32_16x16x32_bf16(af[i], bfr[j], acc[i][j], 0, 0, 0);
    __syncthreads();
  }

  // routing: uniform per block (128 | all boundaries)
  const int tgt = bn >> 4;                          // 0:Q 1:K 2:V 3:F
  unsigned short* oB = (tgt == 0) ? Qb : (tgt == 1) ? Kb : Vb;
  const int coff = tgt * 2048;

#pragma unroll
  for (int i = 0; i < 4; ++i) {
#pragma unroll
    for (int rr = 0; rr < 4; ++rr) {
      int row = bm * 128 + wm * 64 + i * 16 + fq * 4 + rr;
#pragma unroll
      for (int j = 0; j < 4; ++j) {
        int colg = bn * 128 + wn * 64 + j * 16 + fr;
        float val = acc[i][j][rr];
        if (tgt < 3) {
          oB[(size_t)row * 2048 + (colg - coff)] = f2us(swishf(val));
        } else {
          float ls = fminf(val, 0.f) - log1pf(expf(-fabsf(val)));
          Gb[(size_t)row * 512 + (colg - 6144)] = ls * 0.125f;
        }
      }
    }
  }
}

// ------------------------------------------------------------ MFMA GEMM ---
// (fallback tier: W in f32, converted in-kernel)
#define BM 128
#define BN 128
#define BK 32
#define LDSP 40

__global__ __launch_bounds__(256) void mgemm_kernel(
    const unsigned short* __restrict__ A, const float* __restrict__ W,
    unsigned short* __restrict__ outB, float* __restrict__ outF,
    int N, int mode)
{
  __shared__ __align__(16) unsigned short As[BM][LDSP];
  __shared__ __align__(16) unsigned short Bs[BN][LDSP];
  const int bn = blockIdx.x, bm = blockIdx.y, tid = threadIdx.x;
  const int w = tid >> 6, l = tid & 63;
  const int wm = w & 1, wn = w >> 1;
  const int fr = l & 15, fq = l >> 4;

  f32x4 acc[4][4];
#pragma unroll
  for (int i = 0; i < 4; ++i)
#pragma unroll
    for (int j = 0; j < 4; ++j) acc[i][j] = (f32x4){0.f, 0.f, 0.f, 0.f};

  for (int k0 = 0; k0 < DM; k0 += BK) {
#pragma unroll
    for (int s = 0; s < 2; ++s) {
      int chunk = tid + s * 256;
      int row = chunk >> 2;
      int cc = (chunk & 3) * 8;
      *(uint4*)&As[row][cc] =
          *(const uint4*)(A + (size_t)(bm * BM + row) * DM + k0 + cc);
    }
#pragma unroll
    for (int s = 0; s < 4; ++s) {
      int chunk = tid + s * 256;
      int row = chunk >> 3;
      int cc = (chunk & 7) * 4;
      float4 wv = *(const float4*)(W + (size_t)(bn * BN + row) * DM + k0 + cc);
      ushort4 w4;
      w4.x = f2us(wv.x); w4.y = f2us(wv.y); w4.z = f2us(wv.z); w4.w = f2us(wv.w);
      *(ushort4*)&Bs[row][cc] = w4;
    }
    __syncthreads();
    bf16x8 af[4], bfr[4];
#pragma unroll
    for (int i = 0; i < 4; ++i) af[i] = *(const bf16x8*)&As[wm * 64 + i * 16 + fr][fq * 8];
#pragma unroll
    for (int j = 0; j < 4; ++j) bfr[j] = *(const bf16x8*)&Bs[wn * 64 + j * 16 + fr][fq * 8];
#pragma unroll
    for (int i = 0; i < 4; ++i)
#pragma unroll
      for (int j = 0; j < 4; ++j)
        acc[i][j] = __builtin_amdgcn_mfma_f32_16x16x32_bf16(af[i], bfr[j], acc[i][j], 0, 0, 0);
    __syncthreads();
  }

#pragma unroll
  for (int i = 0; i < 4; ++i) {
#pragma unroll
    for (int rr = 0; rr < 4; ++rr) {
      int row = bm * BM + wm * 64 + i * 16 + fq * 4 + rr;
#pragma unroll
      for (int j = 0; j < 4; ++j) {
        int col = bn * BN + wn * 64 + j * 16 + fr;
        float val = acc[i][j][rr];
        size_t idx = (size_t)row * N + col;
        if (mode == MODE_SWISH)      outB[idx] = f2us(swishf(val));
        else if (mode == MODE_F32)   outF[idx] = val;
        else {  // MODE_GATE
          float ls = fminf(val, 0.f) - log1pf(expf(-fabsf(val)));
          outF[idx] = ls * 0.125f;
        }
      }
    }
  }
}

// ------------------------------------------------ Chunked GSA scan (C) ---
// Template: NCH chunks per block; INIT loads gk/gv from Sinit (f32).
// Fallback = <32,false>, grid 32.  Phase C = <4,true>, grid 256.
// (R4-proven form: no register prefetch — 128-VGPR cap forces spills.)
template<int NCH, bool INIT>
__global__ __launch_bounds__(512) void gsa_chunk_t(
    const unsigned short* __restrict__ Q, const unsigned short* __restrict__ K,
    const unsigned short* __restrict__ V, const float* __restrict__ G,
    float* __restrict__ O, const float* __restrict__ DK,
    const float* __restrict__ DV)
{
  // ---- LDS pool, phase-multiplexed (155.1 KiB) ----
  __shared__ __align__(16) char pool[158848];
  auto EB   = (unsigned short(*)[72])(pool + 0);       // e[i][m] bf16 (no XS)
  auto O1B  = (unsigned short(*)[72])(pool + 9216);    // o1[i][m] -> (GvB2 low)
  auto RB   = (unsigned short(*)[72])(pool + 18432);   // r[tau][m] -> (GvB2 hi)
  auto RT   = (unsigned short(*)[72])(pool + 27648);   // r^T[m][tau] -> wT
  auto SB   = (unsigned short(*)[72])(pool + 36864);   // S[i][tau] -> P[i][tau]
  auto UB   = (unsigned short(*)[72])(pool + 46080);   // u[i][m]
  float (*GS)[64] = (float(*)[64])(pool + 55296);      // g staging (f32)
  auto QT   = (unsigned short(*)[264])(pool + 55296);  // q tile [i][d]
  auto KTt2 = (unsigned short(*)[72])(pool + 55296);   // k^T rows d-128
  auto VTt2 = (unsigned short(*)[72])(pool + 55296);   // v^T rows u-128
  auto KT   = (unsigned short(*)[264])(pool + 89088);  // k tile [tau][d]
  auto VTt1 = (unsigned short(*)[72])(pool + 89088);   // v^T rows u<128
  auto GkB  = (unsigned short(*)[264])(pool + 122880); // Gk snapshot [m][d]
  auto KTt1 = (unsigned short(*)[72])(pool + 122880);  // k^T rows d<128
  auto GvB1 = (unsigned short(*)[72])(pool + 122880);  // Gv snapshot u<128
  auto GvB2 = (unsigned short(*)[72])(pool + 9216);    // Gv snapshot u>=128
  float (*red)[68] = (float(*)[68])(pool + 156672);    // prefix partials

  int bh, seg;
  if constexpr (INIT) { bh = (int)blockIdx.x >> 3; seg = (int)blockIdx.x & 7; }
  else                { bh = (int)blockIdx.x; seg = 0; }
  const int b = bh >> 3, h = bh & 7;
  const int tid = threadIdx.x;
  const int w = tid >> 6, l = tid & 63, fr = l & 15, fq = l >> 4;
  const int wlo = w & 3, whi = w >> 2;

  // gk[jj]: (m=wlo*16+fq*4+rr, d=(whi*8+jj)*16+fr)
  // gv[jj]: (u=ut*16+fq*4+rr, m=(jj&3)*16+fr), ut=(w>=4?8:0)+wlo*2+(jj>>2)
  f32x4 gk[8], gv[8];
  if constexpr (INIT) {
    const float* dk = DK + ((size_t)bh * 8 + seg) * 16384;
    const float* dv = DV + ((size_t)bh * 8 + seg) * 16384;
#pragma unroll
    for (int jj = 0; jj < 8; ++jj) {
      int ut = (w >= 4 ? 8 : 0) + wlo * 2 + (jj >> 2);
#pragma unroll
      for (int rr = 0; rr < 4; ++rr) {
        gk[jj][rr] = dk[(wlo * 16 + fq * 4 + rr) * 256 + (whi * 8 + jj) * 16 + fr];
        gv[jj][rr] = dv[(ut * 16 + fq * 4 + rr) * 64 + (jj & 3) * 16 + fr];
      }
    }
  } else {
#pragma unroll
    for (int jj = 0; jj < 8; ++jj) {
      gk[jj] = (f32x4){0.f, 0.f, 0.f, 0.f};
      gv[jj] = (f32x4){0.f, 0.f, 0.f, 0.f};
    }
  }

  for (int cl = 0; cl < NCH; ++cl) {
    const int c = seg * NCH + cl;
    const int rowbase = b * 2048 + c * 64;
    const bool upd = (cl != NCH - 1);  // last chunk's state update is dead

    // ---- ph1a: stage g tile; write Gk bf16 snapshot from regs ----
#pragma unroll
    for (int s = 0; s < 2; ++s) {
      int id = s * 512 + tid, row = id >> 4, mq = id & 15;
      *(float4*)&GS[row][mq * 4] =
          *(const float4*)&G[(size_t)(rowbase + row) * 512 + h * 64 + mq * 4];
    }
#pragma unroll
    for (int jj = 0; jj < 8; ++jj) {
      int dcol = (whi * 8 + jj) * 16 + fr;
#pragma unroll
      for (int rr = 0; rr < 4; ++rr) {
        int grow = wlo * 16 + fq * 4 + rr;
        GkB[grow][XS(grow, dcol)] = f2us(gk[jj][rr]);
      }
    }
    __syncthreads();

    // ---- ph1b: per-8-row partial sums of g (prefix stage 1) ----
    {
      float ps = 0.f;
#pragma unroll
      for (int j = 0; j < 8; ++j) ps += GS[w * 8 + j][l];
      red[w][l] = ps;
    }
    __syncthreads();

    // ---- ph1c: cum, e, r (EB, RB, RT) ----
    {
      float cum = 0.f;
      for (int g2 = 0; g2 < w; ++g2) cum += red[g2][l];
#pragma unroll
      for (int j = 0; j < 8; ++j) {
        int i = w * 8 + j;
        float gval = GS[i][l];
        cum += gval;
        float e = expf(cum);
        float s_ = 1.f - expf(gval);
        float r_ = s_ / e;
        EB[i][l] = f2us(e);
        RB[i][XS(i, l)] = f2us(r_);
        RT[l][XS(l, i)] = f2us(r_);
      }
    }
    __syncthreads();

    // ---- ph2: stage q,k tiles (GS dead) ----
#pragma unroll
    for (int s = 0; s < 4; ++s) {
      int id = s * 512 + tid, row = id >> 5, cc = (id & 31) * 8;
      int sc = XS(row, cc);
      size_t gb = (size_t)(rowbase + row) * 2048 + h * 256 + cc;
      *(uint4*)&QT[row][sc] = *(const uint4*)(Q + gb);
      *(uint4*)&KT[row][sc] = *(const uint4*)(K + gb);
    }
    __syncthreads();

    // ---- ph3: S = QK^T (->SB, causal) and o1 += Q Gk^T ----
    f32x4 o1acc[2];
    o1acc[0] = (f32x4){0.f, 0.f, 0.f, 0.f};
    o1acc[1] = (f32x4){0.f, 0.f, 0.f, 0.f};
    {
      f32x4 sacc[2];
      sacc[0] = (f32x4){0.f, 0.f, 0.f, 0.f};
      sacc[1] = (f32x4){0.f, 0.f, 0.f, 0.f};
      int ar_ = wlo * 16 + fr;
#pragma unroll
      for (int kk = 0; kk < 8; ++kk) {
        bf16x8 aq = *(const bf16x8*)&QT[ar_][XS(ar_, kk * 32 + fq * 8)];
#pragma unroll
        for (int t2 = 0; t2 < 2; ++t2) {
          int tj = (whi + 2 * t2) * 16 + fr;
          int bc = XS(tj, kk * 32 + fq * 8);
          bf16x8 bk = *(const bf16x8*)&KT[tj][bc];
          sacc[t2] = __builtin_amdgcn_mfma_f32_16x16x32_bf16(aq, bk, sacc[t2], 0, 0, 0);
          bf16x8 bg = *(const bf16x8*)&GkB[tj][bc];
          o1acc[t2] = __builtin_amdgcn_mfma_f32_16x16x32_bf16(aq, bg, o1acc[t2], 0, 0, 0);
        }
      }
#pragma unroll
      for (int t2 = 0; t2 < 2; ++t2)
#pragma unroll
        for (int rr = 0; rr < 4; ++rr) {
          int i = wlo * 16 + fq * 4 + rr;
          int tau = (whi + 2 * t2) * 16 + fr;
          SB[i][XS(i, tau)] = f2us(tau <= i ? sacc[t2][rr] : 0.f);
        }
    }
    __syncthreads();

    // ---- ph4: o1 += S r (intra); write O1B = e * o1 ----
    {
      int ar_ = wlo * 16 + fr;
#pragma unroll
      for (int kk = 0; kk < 2; ++kk) {
        bf16x8 as = *(const bf16x8*)&SB[ar_][XS(ar_, kk * 32 + fq * 8)];
#pragma unroll
        for (int t2 = 0; t2 < 2; ++t2) {
          int tj = (whi + 2 * t2) * 16 + fr;
          bf16x8 br = *(const bf16x8*)&RT[tj][XS(tj, kk * 32 + fq * 8)];
          o1acc[t2] = __builtin_amdgcn_mfma_f32_16x16x32_bf16(as, br, o1acc[t2], 0, 0, 0);
        }
      }
#pragma unroll
      for (int t2 = 0; t2 < 2; ++t2)
#pragma unroll
        for (int rr = 0; rr < 4; ++rr) {
          int i = wlo * 16 + fq * 4 + rr;
          int m = (whi + 2 * t2) * 16 + fr;
          O1B[i][XS(i, m)] = f2us(u2f(EB[i][m]) * o1acc[t2][rr]);
        }
    }
    __syncthreads();

    // ---- ph5: softmax rows -> u = qv*e (UB);  wT = e63*r^T in place ----
    {
      int i = tid >> 3, mq = tid & 7;
      int sc = XS(i, mq * 8);
      uint4 raw = *(const uint4*)&O1B[i][sc];
      const unsigned short* rp = (const unsigned short*)&raw;
      float x[8];
#pragma unroll
      for (int j = 0; j < 8; ++j) x[j] = u2f(rp[j]);
      float mx = x[0];
#pragma unroll
      for (int j = 1; j < 8; ++j) mx = fmaxf(mx, x[j]);
      mx = fmaxf(mx, __shfl_xor(mx, 1, 64));
      mx = fmaxf(mx, __shfl_xor(mx, 2, 64));
      mx = fmaxf(mx, __shfl_xor(mx, 4, 64));
      float ex[8], sum = 0.f;
#pragma unroll
      for (int j = 0; j < 8; ++j) { ex[j] = expf(x[j] - mx); sum += ex[j]; }
      sum += __shfl_xor(sum, 1, 64);
      sum += __shfl_xor(sum, 2, 64);
      sum += __shfl_xor(sum, 4, 64);
      float inv = 1.f / sum;
      unsigned short up[8];
#pragma unroll
      for (int j = 0; j < 8; ++j)
        up[j] = f2us(ex[j] * inv * u2f(EB[i][mq * 8 + j]));
      *(uint4*)&UB[i][sc] = *(uint4*)up;
    }
    {
      int m2 = tid >> 3, tq = tid & 7;
      int sc = XS(m2, tq * 8);
      float e63 = u2f(EB[63][m2]);
      uint4 raw = *(const uint4*)&RT[m2][sc];
      const unsigned short* rp = (const unsigned short*)&raw;
      unsigned short ow[8];
#pragma unroll
      for (int j = 0; j < 8; ++j) ow[j] = f2us(u2f(rp[j]) * e63);
      *(uint4*)&RT[m2][sc] = *(uint4*)ow;
    }
    __syncthreads();

    // ---- ph6: P^T = r u^T -> SB (transposed write, causal); K->KTt1 ----
    {
      f32x4 pacc[2];
      pacc[0] = (f32x4){0.f, 0.f, 0.f, 0.f};
      pacc[1] = (f32x4){0.f, 0.f, 0.f, 0.f};
      int ar_ = wlo * 16 + fr;
#pragma unroll
      for (int kk = 0; kk < 2; ++kk) {
        bf16x8 ar = *(const bf16x8*)&RB[ar_][XS(ar_, kk * 32 + fq * 8)];
#pragma unroll
        for (int t2 = 0; t2 < 2; ++t2) {
          int tj = (whi + 2 * t2) * 16 + fr;
          bf16x8 bu = *(const bf16x8*)&UB[tj][XS(tj, kk * 32 + fq * 8)];
          pacc[t2] = __builtin_amdgcn_mfma_f32_16x16x32_bf16(ar, bu, pacc[t2], 0, 0, 0);
        }
      }
#pragma unroll
      for (int t2 = 0; t2 < 2; ++t2)
#pragma unroll
        for (int rr = 0; rr < 4; ++rr) {
          int tau = wlo * 16 + fq * 4 + rr;
          int i = (whi + 2 * t2) * 16 + fr;
          SB[i][XS(i, tau)] = f2us(tau <= i ? pacc[t2][rr] : 0.f);  // PB
        }
    }
    if (upd) {
#pragma unroll
      for (int s = 0; s < 2; ++s) {
        int id = s * 512 + tid, d8 = id & 15, tau = id >> 4;
        uint4 raw = *(const uint4*)&KT[tau][XS(tau, d8 * 8)];
        const unsigned short* rp = (const unsigned short*)&raw;
#pragma unroll
        for (int j = 0; j < 8; ++j) {
          int trow = d8 * 8 + j;
          KTt1[trow][XS(trow, tau)] = rp[j];
        }
      }
    }
    __syncthreads();

    // ---- ph7a: waves0-3: Gk update (d<128);  waves4-7: K->KTt2 ----
    if (upd) {
      if (w < 4) {
        float e63r[4];
#pragma unroll
        for (int rr = 0; rr < 4; ++rr) e63r[rr] = u2f(EB[63][wlo * 16 + fq * 4 + rr]);
        int wr = wlo * 16 + fr;
        bf16x8 aw0 = *(const bf16x8*)&RT[wr][XS(wr, fq * 8)];
        bf16x8 aw1 = *(const bf16x8*)&RT[wr][XS(wr, 32 + fq * 8)];
#pragma unroll
        for (int jj = 0; jj < 8; ++jj) {
#pragma unroll
          for (int rr = 0; rr < 4; ++rr) gk[jj][rr] *= e63r[rr];
          int kr = jj * 16 + fr;
          bf16x8 bk0 = *(const bf16x8*)&KTt1[kr][XS(kr, fq * 8)];
          bf16x8 bk1 = *(const bf16x8*)&KTt1[kr][XS(kr, 32 + fq * 8)];
          gk[jj] = __builtin_amdgcn_mfma_f32_16x16x32_bf16(aw0, bk0, gk[jj], 0, 0, 0);
          gk[jj] = __builtin_amdgcn_mfma_f32_16x16x32_bf16(aw1, bk1, gk[jj], 0, 0, 0);
        }
      } else {
#pragma unroll
        for (int s = 0; s < 4; ++s) {
          int id = s * 256 + (tid - 256), d8 = id & 15, tau = id >> 4;
          uint4 raw = *(const uint4*)&KT[tau][XS(tau, 128 + d8 * 8)];
          const unsigned short* rp = (const unsigned short*)&raw;
#pragma unroll
          for (int j = 0; j < 8; ++j) {
            int trow = d8 * 8 + j;
            KTt2[trow][XS(trow, tau)] = rp[j];
          }
        }
      }
    }
    __syncthreads();

    // ---- ph7b: waves4-7: Gk update (d>=128); waves0-3: VTt1 + GvB1 ----
    if (upd && w >= 4) {
      float e63r[4];
#pragma unroll
      for (int rr = 0; rr < 4; ++rr) e63r[rr] = u2f(EB[63][wlo * 16 + fq * 4 + rr]);
      int wr = wlo * 16 + fr;
      bf16x8 aw0 = *(const bf16x8*)&RT[wr][XS(wr, fq * 8)];
      bf16x8 aw1 = *(const bf16x8*)&RT[wr][XS(wr, 32 + fq * 8)];
#pragma unroll
      for (int jj = 0; jj < 8; ++jj) {
#pragma unroll
        for (int rr = 0; rr < 4; ++rr) gk[jj][rr] *= e63r[rr];
        int kr = jj * 16 + fr;
        bf16x8 bk0 = *(const bf16x8*)&KTt2[kr][XS(kr, fq * 8)];
        bf16x8 bk1 = *(const bf16x8*)&KTt2[kr][XS(kr, 32 + fq * 8)];
        gk[jj] = __builtin_amdgcn_mfma_f32_16x16x32_bf16(aw0, bk0, gk[jj], 0, 0, 0);
        gk[jj] = __builtin_amdgcn_mfma_f32_16x16x32_bf16(aw1, bk1, gk[jj], 0, 0, 0);
      }
    }
    if (w < 4) {
#pragma unroll
      for (int s = 0; s < 4; ++s) {
        int id = s * 256 + tid, u8 = id & 15, tau = id >> 4;
        uint4 raw = *(const uint4*)(V + (size_t)(rowbase + tau) * 2048 + h * 256 + u8 * 8);
        const unsigned short* rp = (const unsigned short*)&raw;
#pragma unroll
        for (int j = 0; j < 8; ++j) {
          int trow = u8 * 8 + j;
          VTt1[trow][XS(trow, tau)] = rp[j];
        }
      }
#pragma unroll
      for (int jj = 0; jj < 8; ++jj) {
        int u0 = (wlo * 2 + (jj >> 2)) * 16 + fq * 4;
        int m = (jj & 3) * 16 + fr;
#pragma unroll
        for (int rr = 0; rr < 4; ++rr) {
          int grow = u0 + rr;
          GvB1[grow][XS(grow, m)] = f2us(gv[jj][rr]);
        }
      }
    }
    __syncthreads();

    // ---- ph8: o(u<128) -> O ; w<4: Gv upd h1; VTt2 stage; w>=4: GvB2 ----
    {
      int pr = wlo * 16 + fr;
      bf16x8 ap0 = *(const bf16x8*)&SB[pr][XS(pr, fq * 8)];
      bf16x8 ap1 = *(const bf16x8*)&SB[pr][XS(pr, 32 + fq * 8)];
      bf16x8 au0 = *(const bf16x8*)&UB[pr][XS(pr, fq * 8)];
      bf16x8 au1 = *(const bf16x8*)&UB[pr][XS(pr, 32 + fq * 8)];
#pragma unroll
      for (int oo = 0; oo < 4; ++oo) {
        int ut = whi * 4 + oo;
        int vr = ut * 16 + fr;
        f32x4 oa = (f32x4){0.f, 0.f, 0.f, 0.f};
        bf16x8 bv0 = *(const bf16x8*)&VTt1[vr][XS(vr, fq * 8)];
        bf16x8 bv1 = *(const bf16x8*)&VTt1[vr][XS(vr, 32 + fq * 8)];
        bf16x8 bg0 = *(const bf16x8*)&GvB1[vr][XS(vr, fq * 8)];
        bf16x8 bg1 = *(const bf16x8*)&GvB1[vr][XS(vr, 32 + fq * 8)];
        oa = __builtin_amdgcn_mfma_f32_16x16x32_bf16(ap0, bv0, oa, 0, 0, 0);
        oa = __builtin_amdgcn_mfma_f32_16x16x32_bf16(ap1, bv1, oa, 0, 0, 0);
        oa = __builtin_amdgcn_mfma_f32_16x16x32_bf16(au0, bg0, oa, 0, 0, 0);
        oa = __builtin_amdgcn_mfma_f32_16x16x32_bf16(au1, bg1, oa, 0, 0, 0);
#pragma unroll
        for (int rr = 0; rr < 4; ++rr)
          O[(size_t)(rowbase + wlo * 16 + fq * 4 + rr) * 2048 + h * 256 + ut * 16 + fr] = oa[rr];
      }
    }
#pragma unroll
    for (int s = 0; s < 2; ++s) {
      int id = s * 512 + tid, u8 = id & 15, tau = id >> 4;
      uint4 raw = *(const uint4*)(V + (size_t)(rowbase + tau) * 2048 + h * 256 + 128 + u8 * 8);
      const unsigned short* rp = (const unsigned short*)&raw;
#pragma unroll
      for (int j = 0; j < 8; ++j) {
        int trow = u8 * 8 + j;
        VTt2[trow][XS(trow, tau)] = rp[j];
      }
    }
    if (w < 4) {
      if (upd) {
#pragma unroll
        for (int jj = 0; jj < 8; ++jj) {
          int ut = wlo * 2 + (jj >> 2), mt = jj & 3;
          float e63v = u2f(EB[63][mt * 16 + fr]);
#pragma unroll
          for (int rr = 0; rr < 4; ++rr) gv[jj][rr] *= e63v;
          int vr = ut * 16 + fr, br_ = mt * 16 + fr;
          bf16x8 av0 = *(const bf16x8*)&VTt1[vr][XS(vr, fq * 8)];
          bf16x8 av1 = *(const bf16x8*)&VTt1[vr][XS(vr, 32 + fq * 8)];
          bf16x8 bw0 = *(const bf16x8*)&RT[br_][XS(br_, fq * 8)];
          bf16x8 bw1 = *(const bf16x8*)&RT[br_][XS(br_, 32 + fq * 8)];
          gv[jj] = __builtin_amdgcn_mfma_f32_16x16x32_bf16(av0, bw0, gv[jj], 0, 0, 0);
          gv[jj] = __builtin_amdgcn_mfma_f32_16x16x32_bf16(av1, bw1, gv[jj], 0, 0, 0);
        }
      }
    } else {
#pragma unroll
      for (int jj = 0; jj < 8; ++jj) {
        int u0 = (wlo * 2 + (jj >> 2)) * 16 + fq * 4;
        int m = (jj & 3) * 16 + fr;
#pragma unroll
        for (int rr = 0; rr < 4; ++rr) {
          int grow = u0 + rr;
          GvB2[grow][XS(grow, m)] = f2us(gv[jj][rr]);
        }
      }
    }
    __syncthreads();

    // ---- ph9: o(u>=128) -> O ; waves4-7: Gv upd h2 ----
    {
      int pr = wlo * 16 + fr;
      bf16x8 ap0 = *(const bf16x8*)&SB[pr][XS(pr, fq * 8)];
      bf16x8 ap1 = *(const bf16x8*)&SB[pr][XS(pr, 32 + fq * 8)];
      bf16x8 au0 = *(const bf16x8*)&UB[pr][XS(pr, fq * 8)];
      bf16x8 au1 = *(const bf16x8*)&UB[pr][XS(pr, 32 + fq * 8)];
#pragma unroll
      for (int oo = 0; oo < 4; ++oo) {
        int utl = whi * 4 + oo;  // local u-tile (global ut = 8+utl)
        int vr = utl * 16 + fr;
        f32x4 oa = (f32x4){0.f, 0.f, 0.f, 0.f};
        bf16x8 bv0 = *(const bf16x8*)&VTt2[vr][XS(vr, fq * 8)];
        bf16x8 bv1 = *(const bf16x8*)&VTt2[vr][XS(vr, 32 + fq * 8)];
        bf16x8 bg0 = *(const bf16x8*)&GvB2[vr][XS(vr, fq * 8)];
        bf16x8 bg1 = *(const bf16x8*)&GvB2[vr][XS(vr, 32 + fq * 8)];
        oa = __builtin_amdgcn_mfma_f32_16x16x32_bf16(ap0, bv0, oa, 0, 0, 0);
        oa = __builtin_amdgcn_mfma_f32_16x16x32_bf16(ap1, bv1, oa, 0, 0, 0);
        oa = __builtin_amdgcn_mfma_f32_16x16x32_bf16(au0, bg0, oa, 0, 0, 0);
        oa = __builtin_amdgcn_mfma_f32_16x16x32_bf16(au1, bg1, oa, 0, 0, 0);
#pragma unroll
        for (int rr = 0; rr < 4; ++rr)
          O[(size_t)(rowbase + wlo * 16 + fq * 4 + rr) * 2048 + h * 256 + 128 + utl * 16 + fr] = oa[rr];
      }
    }
    if (upd && w >= 4) {
#pragma unroll
      for (int jj = 0; jj < 8; ++jj) {
        int utl = wlo * 2 + (jj >> 2), mt = jj & 3;
        float e63v = u2f(EB[63][mt * 16 + fr]);
#pragma unroll
        for (int rr = 0; rr < 4; ++rr) gv[jj][rr] *= e63v;
        int vr = utl * 16 + fr, br_ = mt * 16 + fr;
        bf16x8 av0 = *(const bf16x8*)&VTt2[vr][XS(vr, fq * 8)];
        bf16x8 av1 = *(const bf16x8*)&VTt2[vr][XS(vr, 32 + fq * 8)];
        bf16x8 bw0 = *(const bf16x8*)&RT[br_][XS(br_, fq * 8)];
        bf16x8 bw1 = *(const bf16x8*)&RT[br_][XS(br_, 32 + fq * 8)];
        gv[jj] = __builtin_amdgcn_mfma_f32_16x16x32_bf16(av0, bw0, gv[jj], 0, 0, 0);
        gv[jj] = __builtin_amdgcn_mfma_f32_16x16x32_bf16(av1, bw1, gv[jj], 0, 0, 0);
      }
    }
    __syncthreads();
  }
}

// --------------------------------------------- Phase A: segment deltas ---
__global__ __launch_bounds__(512) void gsa_segA_kernel(
    const unsigned short* __restrict__ K, const unsigned short* __restrict__ V,
    const float* __restrict__ G, float* __restrict__ DK, float* __restrict__ DV,
    float* __restrict__ ES)
{
  __shared__ __align__(16) char pool[135552];
  float (*GS)[64] = (float(*)[64])(pool);             // 16384
  float (*red)[68] = (float(*)[68])(pool + 16384);    // 2176
  auto RT   = (unsigned short(*)[72])(pool + 18560);  // 9216
  float* e63f = (float*)(pool + 27776);               // 256
  auto KT   = (unsigned short(*)[264])(pool + 28032); // 33792
  auto KTt1 = (unsigned short(*)[72])(pool + 61824);  // 18432
  auto KTt2 = (unsigned short(*)[72])(pool + 80256);
  auto VTt1 = (unsigned short(*)[72])(pool + 98688);
  auto VTt2 = (unsigned short(*)[72])(pool + 117120); // end 135552

  const int bh = (int)blockIdx.x >> 3, seg = (int)blockIdx.x & 7;
  const int b = bh >> 3, h = bh & 7;
  const int tid = threadIdx.x;
  const int w = tid >> 6, l = tid & 63, fr = l & 15, fq = l >> 4;
  const int wlo = w & 3, whi = w >> 2;

  f32x4 gk[8], gv[8];
#pragma unroll
  for (int jj = 0; jj < 8; ++jj) {
    gk[jj] = (f32x4){0.f, 0.f, 0.f, 0.f};
    gv[jj] = (f32x4){0.f, 0.f, 0.f, 0.f};
  }
  float gsum = 0.f;  // valid on w==7 threads

  for (int cl = 0; cl < 4; ++cl) {
    const int rowbase = b * 2048 + (seg * 4 + cl) * 64;

    // ph1: stage G + K
#pragma unroll
    for (int s = 0; s < 2; ++s) {
      int id = s * 512 + tid, row = id >> 4, mq = id & 15;
      *(float4*)&GS[row][mq * 4] =
          *(const float4*)&G[(size_t)(rowbase + row) * 512 + h * 64 + mq * 4];
    }
#pragma unroll
    for (int s = 0; s < 4; ++s) {
      int id = s * 512 + tid, row = id >> 5, cc = (id & 31) * 8;
      *(uint4*)&KT[row][XS(row, cc)] =
          *(const uint4*)(K + (size_t)(rowbase + row) * 2048 + h * 256 + cc);
    }
    __syncthreads();

    // ph2: prefix partials
    {
      float ps = 0.f;
#pragma unroll
      for (int j = 0; j < 8; ++j) ps += GS[w * 8 + j][l];
      red[w][l] = ps;
    }
    __syncthreads();

    // ph3: cum -> RT (r^T), e63, segment g-sum
    {
      float cum = 0.f;
      for (int g2 = 0; g2 < w; ++g2) cum += red[g2][l];
#pragma unroll
      for (int j = 0; j < 8; ++j) {
        int i = w * 8 + j;
        float gval = GS[i][l];
        cum += gval;
        float e = expf(cum);
        float r_ = (1.f - expf(gval)) / e;
        RT[l][XS(l, i)] = f2us(r_);
      }
      if (w == 7) { gsum += cum; e63f[l] = expf(cum); }
    }
    __syncthreads();

    // ph4: RT *= e63 (-> w^T); K transposes; V transposes (from global)
    {
      int m2 = tid >> 3, tq = tid & 7;
      int sc = XS(m2, tq * 8);
      float e63 = e63f[m2];
      uint4 raw = *(const uint4*)&RT[m2][sc];
      const unsigned short* rp = (const unsigned short*)&raw;
      unsigned short ow[8];
#pragma unroll
      for (int j = 0; j < 8; ++j) ow[j] = f2us(u2f(rp[j]) * e63);
      *(uint4*)&RT[m2][sc] = *(uint4*)ow;
    }
#pragma unroll
    for (int s = 0; s < 2; ++s) {
      int id = s * 512 + tid, d8 = id & 15, tau = id >> 4;
      uint4 raw1 = *(const uint4*)&KT[tau][XS(tau, d8 * 8)];
      uint4 raw2 = *(const uint4*)&KT[tau][XS(tau, 128 + d8 * 8)];
      const unsigned short* rp1 = (const unsigned short*)&raw1;
      const unsigned short* rp2 = (const unsigned short*)&raw2;
#pragma unroll
      for (int j = 0; j < 8; ++j) {
        int trow = d8 * 8 + j;
        KTt1[trow][XS(trow, tau)] = rp1[j];
        KTt2[trow][XS(trow, tau)] = rp2[j];
      }
    }
#pragma unroll
    for (int s = 0; s < 2; ++s) {
      int id = s * 512 + tid, u8 = id & 15, tau = id >> 4;
      size_t gb = (size_t)(rowbase + tau) * 2048 + h * 256 + u8 * 8;
      uint4 raw1 = *(const uint4*)(V + gb);
      uint4 raw2 = *(const uint4*)(V + gb + 128);
      const unsigned short* rp1 = (const unsigned short*)&raw1;
      const unsigned short* rp2 = (const unsigned short*)&raw2;
#pragma unroll
      for (int j = 0; j < 8; ++j) {
        int trow = u8 * 8 + j;
        VTt1[trow][XS(trow, tau)] = rp1[j];
        VTt2[trow][XS(trow, tau)] = rp2[j];
      }
    }
    __syncthreads();

    // ph5: gk += w^T K ; gv += V^T w
    {
      float e63r[4];
#pragma unroll
      for (int rr = 0; rr < 4; ++rr) e63r[rr] = e63f[wlo * 16 + fq * 4 + rr];
      int wr = wlo * 16 + fr;
      bf16x8 aw0 = *(const bf16x8*)&RT[wr][XS(wr, fq * 8)];
      bf16x8 aw1 = *(const bf16x8*)&RT[wr][XS(wr, 32 + fq * 8)];
      auto KTx = (w < 4) ? KTt1 : KTt2;
#pragma unroll
      for (int jj = 0; jj < 8; ++jj) {
#pragma unroll
        for (int rr = 0; rr < 4; ++rr) gk[jj][rr] *= e63r[rr];
        int kr = jj * 16 + fr;
        bf16x8 bk0 = *(const bf16x8*)&KTx[kr][XS(kr, fq * 8)];
        bf16x8 bk1 = *(const bf16x8*)&KTx[kr][XS(kr, 32 + fq * 8)];
        gk[jj] = __builtin_amdgcn_mfma_f32_16x16x32_bf16(aw0, bk0, gk[jj], 0, 0, 0);
        gk[jj] = __builtin_amdgcn_mfma_f32_16x16x32_bf16(aw1, bk1, gk[jj], 0, 0, 0);
      }
      auto VTx = (w < 4) ? VTt1 : VTt2;
#pragma unroll
      for (int jj = 0; jj < 8; ++jj) {
        int utl = wlo * 2 + (jj >> 2), mt = jj & 3;
        float e63v = e63f[mt * 16 + fr];
#pragma unroll
        for (int rr = 0; rr < 4; ++rr) gv[jj][rr] *= e63v;
        int vr = utl * 16 + fr, br_ = mt * 16 + fr;
        bf16x8 av0 = *(const bf16x8*)&VTx[vr][XS(vr, fq * 8)];
        bf16x8 av1 = *(const bf16x8*)&VTx[vr][XS(vr, 32 + fq * 8)];
        bf16x8 bw0 = *(const bf16x8*)&RT[br_][XS(br_, fq * 8)];
        bf16x8 bw1 = *(const bf16x8*)&RT[br_][XS(br_, 32 + fq * 8)];
        gv[jj] = __builtin_amdgcn_mfma_f32_16x16x32_bf16(av0, bw0, gv[jj], 0, 0, 0);
        gv[jj] = __builtin_amdgcn_mfma_f32_16x16x32_bf16(av1, bw1, gv[jj], 0, 0, 0);
      }
    }
    __syncthreads();
  }

  // write deltas + segment decay
  float* dk = DK + ((size_t)bh * 8 + seg) * 16384;
  float* dv = DV + ((size_t)bh * 8 + seg) * 16384;
#pragma unroll
  for (int jj = 0; jj < 8; ++jj) {
    int ut = (w >= 4 ? 8 : 0) + wlo * 2 + (jj >> 2);
#pragma unroll
    for (int rr = 0; rr < 4; ++rr) {
      dk[(wlo * 16 + fq * 4 + rr) * 256 + (whi * 8 + jj) * 16 + fr] = gk[jj][rr];
      dv[(ut * 16 + fq * 4 + rr) * 64 + (jj & 3) * 16 + fr] = gv[jj][rr];
    }
  }
  if (w == 7) ES[((size_t)bh * 8 + seg) * 64 + l] = expf(gsum);
}

// ------------------------------------------- Phase B: prefix combine ---
__global__ __launch_bounds__(1024) void gsa_segB_kernel(
    float* __restrict__ DK, float* __restrict__ DV, const float* __restrict__ ES)
{
  const int bh = blockIdx.x, tid = threadIdx.x;
  __shared__ float es[8][64];
  if (tid < 512) es[tid >> 6][tid & 63] = ES[(size_t)bh * 512 + tid];
  __syncthreads();
  float* dk = DK + (size_t)bh * 8 * 16384;
  float* dv = DV + (size_t)bh * 8 * 16384;
  for (int k = 0; k < 16; ++k) {
    int e = k * 1024 + tid;
    int m = e >> 8;                 // DK: e = m*256 + d
    float S = 0.f;
#pragma unroll
    for (int s = 0; s < 8; ++s) {
      float d = dk[s * 16384 + e];
      dk[s * 16384 + e] = S;
      S = fmaf(S, es[s][m], d);
    }
  }
  for (int k = 0; k < 16; ++k) {
    int e = k * 1024 + tid;
    int m = e & 63;                 // DV: e = u*64 + m
    float S = 0.f;
#pragma unroll
    for (int s = 0; s < 8; ++s) {
      float d = dv[s * 16384 + e];
      dv[s * 16384 + e] = S;
      S = fmaf(S, es[s][m], d);
    }
  }
}

// ------------------------------------------------------------- sentinel ---
__global__ __launch_bounds__(256) void fillf_kernel(float* o, float v) {
  o[(size_t)blockIdx.x * 256 + threadIdx.x] = v;
}

// --------------------------------------------------------------- launch ---
extern "C" void kernel_launch(void* const* d_in, const int* in_sizes, int n_in,
                              void* d_out, int out_size, void* d_ws, size_t ws_size,
                              hipStream_t stream)
{
  const float* hidden   = (const float*)d_in[0];
  const float* norm_w   = (const float*)d_in[1];
  const float* q_w      = (const float*)d_in[2];
  const float* k_w      = (const float*)d_in[3];
  const float* v_w      = (const float*)d_in[4];
  const float* f_w      = (const float*)d_in[5];
  const float* g_norm_w = (const float*)d_in[6];
  const float* o_w      = (const float*)d_in[7];

  float* dout = (float*)d_out;
  char* ws = (char*)d_ws;
  const size_t SZB = (size_t)ROWS * DM * 2;        // 32MiB bf16 activation
  const size_t SZG = (size_t)ROWS * 512 * 4;       // 16MiB f32 gates
  const size_t NEED = 4 * SZB + SZG;               // 144MiB
  const size_t SZD = (size_t)32 * 8 * 16384 * 4;   // 16MiB per delta array
  const size_t NEED_BIG = NEED + 2 * SZD + (size_t)32 * 8 * 64 * 4;
  const size_t SZWB = (size_t)DM * DM * 2;         // 8MiB bf16 weight
  const size_t SZWF = (size_t)512 * DM * 2;        // 2MiB bf16 f-weight
  const size_t NEED_W = NEED_BIG + 4 * SZWB + SZWF;

  if (ws_size < NEED) {
    fillf_kernel<<<65536, 256, 0, stream>>>(dout, 123.0f);
    return;
  }

  unsigned short* XN = (unsigned short*)(ws);      // xnorm, later o_act
  unsigned short* Qb = (unsigned short*)(ws + SZB);
  unsigned short* Kb = (unsigned short*)(ws + 2 * SZB);
  unsigned short* Vb = (unsigned short*)(ws + 3 * SZB);
  float* Gb          = (float*)(ws + 4 * SZB);
  float* DK          = (float*)(ws + NEED);
  float* DV          = DK + (size_t)32 * 8 * 16384;
  float* ES          = DV + (size_t)32 * 8 * 16384;
  // weight layout: WQ,WK,WV,WF contiguous (fused GEMM), then WO.
  unsigned short* WQ = (unsigned short*)(ws + NEED_BIG);
  unsigned short* WK = WQ + (size_t)2048 * 2048;
  unsigned short* WV = WK + (size_t)2048 * 2048;
  unsigned short* WF = WV + (size_t)2048 * 2048;
  unsigned short* WO = WF + (size_t)512 * 2048;

  xnorm_kernel<<<ROWS, 256, 0, stream>>>(hidden, norm_w, XN);

  if (ws_size >= NEED_W) {
    // weight pre-conversion (f32 -> bf16, RNE; same rounding as before)
    wconv_kernel<<<2048, 256, 0, stream>>>(q_w, WQ);
    wconv_kernel<<<2048, 256, 0, stream>>>(k_w, WK);
    wconv_kernel<<<2048, 256, 0, stream>>>(v_w, WV);
    wconv_kernel<<<512, 256, 0, stream>>>(f_w, WF);
    wconv_kernel<<<2048, 256, 0, stream>>>(o_w, WO);

    // fused Q/K/V/F projection: N=6656, grid 52x64 (nwg=3328 %8==0)
    mgemm2_fused_kernel<<<dim3(52, 64), 256, 0, stream>>>(XN, WQ, Qb, Kb, Vb, Gb);
  } else {
    mgemm_kernel<<<dim3(16, 64), 256, 0, stream>>>(XN, q_w, Qb, nullptr, 2048, MODE_SWISH);
    mgemm_kernel<<<dim3(16, 64), 256, 0, stream>>>(XN, k_w, Kb, nullptr, 2048, MODE_SWISH);
    mgemm_kernel<<<dim3(16, 64), 256, 0, stream>>>(XN, v_w, Vb, nullptr, 2048, MODE_SWISH);
    mgemm_kernel<<<dim3(4, 64), 256, 0, stream>>>(XN, f_w, nullptr, Gb, 512, MODE_GATE);
  }

  if (ws_size >= NEED_BIG) {
    gsa_segA_kernel<<<256, 512, 0, stream>>>(Kb, Vb, Gb, DK, DV, ES);
    gsa_segB_kernel<<<32, 1024, 0, stream>>>(DK, DV, ES);
    gsa_chunk_t<4, true><<<256, 512, 0, stream>>>(Qb, Kb, Vb, Gb, dout, DK, DV);
  } else {
    gsa_chunk_t<32, false><<<32, 512, 0, stream>>>(Qb, Kb, Vb, Gb, dout, nullptr, nullptr);
  }

  oact_norm_kernel<<<ROWS, 256, 0, stream>>>(dout, g_norm_w, XN);

  if (ws_size >= NEED_W)
    mgemm2_kernel<<<dim3(16, 64), 256, 0, stream>>>(XN, WO, nullptr, dout, 2048, MODE_F32);
  else
    mgemm_kernel<<<dim3(16, 64), 256, 0, stream>>>(XN, o_w, nullptr, dout, 2048, MODE_F32);
}

// Round 8
// 837.765 us; speedup vs baseline: 1.2236x; 1.0165x over previous
//
#include <hip/hip_runtime.h>
#include <hip/hip_bf16.h>
#include <math.h>

// Gated Slot Attention. Inputs f32, output f32.
// ROUND 16: GEMM L2-locality fix. R7's fused GEMM showed FETCH=691MB vs
// 59MB working set (12x over-fetch): bn-fast intra-XCD order streams the
// whole 27MB W per bm-row through the 4MB L2. New mapping: bm=xcd*8+
// (local&7), bn=local>>3 -> XCD's 8 A-panels (4MB = one L2) resident,
// each W-panel used by 8 consecutive blocks then dropped. Same mapping
// for the O-projection mgemm2. Scan kernels unchanged (R4-proven form).

typedef __bf16 bf16x8 __attribute__((ext_vector_type(8)));
typedef float f32x4 __attribute__((ext_vector_type(4)));

#define ROWS 8192   // B*T
#define DM 2048

#define MODE_F32 0
#define MODE_SWISH 1
#define MODE_GATE 2

// LDS bank-conflict swizzle for the scan buffers (stride 72/264 shorts).
#define XS(r, c) ((c) ^ ((r) & 56))

__device__ __forceinline__ float u2f(unsigned short u) {
  union { unsigned int i; float f; } cv; cv.i = ((unsigned int)u) << 16; return cv.f;
}
__device__ __forceinline__ unsigned short f2us(float f) {
  return __builtin_bit_cast(unsigned short, __float2bfloat16(f));
}
__device__ __forceinline__ float swishf(float v) { return v / (1.f + expf(-v)); }

// async global->LDS, 16B per lane; LDS dest = wave-uniform base + lane*16.
__device__ __forceinline__ void gload16(const void* g, void* l) {
  __builtin_amdgcn_global_load_lds(
      (const __attribute__((address_space(1))) void*)g,
      (__attribute__((address_space(3))) void*)l, 16, 0, 0);
}

// --------------------------------------------------------------- xnorm ---
__global__ __launch_bounds__(256) void xnorm_kernel(
    const float* __restrict__ in, const float* __restrict__ w,
    unsigned short* __restrict__ out)
{
  const int row = blockIdx.x, tid = threadIdx.x;
  const size_t base = (size_t)row * DM + tid * 8;
  float a[8];
#pragma unroll
  for (int i = 0; i < 8; ++i) a[i] = in[base + i];
  float ss = 0.f;
#pragma unroll
  for (int i = 0; i < 8; ++i) ss += a[i] * a[i];
#pragma unroll
  for (int off = 32; off; off >>= 1) ss += __shfl_xor(ss, off, 64);
  __shared__ float wsum[4];
  if ((tid & 63) == 0) wsum[tid >> 6] = ss;
  __syncthreads();
  float tot = wsum[0] + wsum[1] + wsum[2] + wsum[3];
  float rstd = rsqrtf(tot * (1.f / (float)DM) + 1e-5f);
#pragma unroll
  for (int i = 0; i < 8; ++i)
    out[base + i] = f2us(a[i] * rstd * w[tid * 8 + i]);
}

// ---------------------------------------------------------- oact_norm ---
__global__ __launch_bounds__(256) void oact_norm_kernel(
    const float* __restrict__ o, const float* __restrict__ w,
    unsigned short* __restrict__ out)
{
  const int row = blockIdx.x, tid = threadIdx.x;
  const size_t base = (size_t)row * DM + tid * 8;
  float a[8];
#pragma unroll
  for (int i = 0; i < 8; ++i) a[i] = swishf(o[base + i]);
  float ss = 0.f;
#pragma unroll
  for (int i = 0; i < 8; ++i) ss += a[i] * a[i];
#pragma unroll
  for (int off = 32; off; off >>= 1) ss += __shfl_xor(ss, off, 64);
  __shared__ float wsum[4];
  if ((tid & 63) == 0) wsum[tid >> 6] = ss;
  __syncthreads();
  float tot = wsum[0] + wsum[1] + wsum[2] + wsum[3];
  float rstd = rsqrtf(tot * (1.f / (float)DM) + 1e-5f);
#pragma unroll
  for (int i = 0; i < 8; ++i)
    out[base + i] = f2us(a[i] * rstd * w[tid * 8 + i]);
}

// -------------------------------------------------- weight f32->bf16 ---
__global__ __launch_bounds__(256) void wconv_kernel(
    const float* __restrict__ in, unsigned short* __restrict__ out)
{
  size_t i = ((size_t)blockIdx.x * 256 + threadIdx.x) * 8;
  float4 a = *(const float4*)(in + i);
  float4 b = *(const float4*)(in + i + 4);
  unsigned short u[8] = {f2us(a.x), f2us(a.y), f2us(a.z), f2us(a.w),
                         f2us(b.x), f2us(b.y), f2us(b.z), f2us(b.w)};
  *(uint4*)(out + i) = *(const uint4*)u;
}

// ------------------------------------------- MFMA GEMM v2 (glds) ---
// C[m,n] = epilogue( sum_k A[m,k]*WB[n,k] ); A,WB bf16 row-major K=2048.
// 128x128 tile, BK=32, 2x2 waves of 64x64, 16x16x32 bf16 MFMA.
// LDS tile linear (glds dest); chunk swizzle cb^=(row>>1)&3 on global
// source + reads. XCD mapping: bm=xcd*8+(local&7), bn=local>>3
// (requires gridDim.y==64; bijective; A-panels resident in L2).
__global__ __launch_bounds__(256) void mgemm2_kernel(
    const unsigned short* __restrict__ A, const unsigned short* __restrict__ WB,
    unsigned short* __restrict__ outB, float* __restrict__ outF,
    int N, int mode)
{
  __shared__ __align__(16) unsigned short As[128 * 32];
  __shared__ __align__(16) unsigned short Bs[128 * 32];
  const int tid = threadIdx.x;
  const int bid = (int)(blockIdx.y * gridDim.x + blockIdx.x);
  const int xcd = bid & 7, local = bid >> 3;
  const int bm = xcd * 8 + (local & 7);
  const int bn = local >> 3;
  const int w = tid >> 6, l = tid & 63;
  const int wm = w & 1, wn = w >> 1;
  const int fr = l & 15, fq = l >> 4;

  f32x4 acc[4][4];
#pragma unroll
  for (int i = 0; i < 4; ++i)
#pragma unroll
    for (int j = 0; j < 4; ++j) acc[i][j] = (f32x4){0.f, 0.f, 0.f, 0.f};

  // staging geometry: physical chunk p = w*128 + j*64 + l
  int prow[2], pcol[2];
#pragma unroll
  for (int j = 0; j < 2; ++j) {
    int p = w * 128 + j * 64 + l;
    prow[j] = p >> 2;
    pcol[j] = ((p & 3) ^ ((prow[j] >> 1) & 3)) * 8;  // element offset in row
  }
  const size_t abase = (size_t)(bm * 128) * DM;
  const size_t bbase = (size_t)(bn * 128) * DM;

  for (int k0 = 0; k0 < DM; k0 += 32) {
#pragma unroll
    for (int j = 0; j < 2; ++j) {
      gload16(A + abase + (size_t)prow[j] * DM + k0 + pcol[j],
              &As[(w * 128 + j * 64) * 8]);
      gload16(WB + bbase + (size_t)prow[j] * DM + k0 + pcol[j],
              &Bs[(w * 128 + j * 64) * 8]);
    }
    __syncthreads();
    bf16x8 af[4], bfr[4];
#pragma unroll
    for (int i = 0; i < 4; ++i) {
      int row = wm * 64 + i * 16 + fr;
      af[i] = *(const bf16x8*)&As[row * 32 + ((fq ^ ((row >> 1) & 3)) * 8)];
    }
#pragma unroll
    for (int j = 0; j < 4; ++j) {
      int row = wn * 64 + j * 16 + fr;
      bfr[j] = *(const bf16x8*)&Bs[row * 32 + ((fq ^ ((row >> 1) & 3)) * 8)];
    }
#pragma unroll
    for (int i = 0; i < 4; ++i)
#pragma unroll
      for (int j = 0; j < 4; ++j)
        acc[i][j] = __builtin_amdgcn_mfma_f32_16x16x32_bf16(af[i], bfr[j], acc[i][j], 0, 0, 0);
    __syncthreads();
  }

#pragma unroll
  for (int i = 0; i < 4; ++i) {
#pragma unroll
    for (int rr = 0; rr < 4; ++rr) {
      int row = bm * 128 + wm * 64 + i * 16 + fq * 4 + rr;
#pragma unroll
      for (int j = 0; j < 4; ++j) {
        int col = bn * 128 + wn * 64 + j * 16 + fr;
        float val = acc[i][j][rr];
        size_t idx = (size_t)row * N + col;
        if (mode == MODE_SWISH)      outB[idx] = f2us(swishf(val));
        else if (mode == MODE_F32)   outF[idx] = val;
        else {  // MODE_GATE
          float ls = fminf(val, 0.f) - log1pf(expf(-fabsf(val)));
          outF[idx] = ls * 0.125f;
        }
      }
    }
  }
}

// -------------------------------- fused Q/K/V/F projection GEMM ---
// WALL = [WQ;WK;WV;WF] bf16 [6656][2048]. Grid 52x64 (nwg=3328, %8==0).
// bn in [0,16)->Qb swish; [16,32)->Kb; [32,48)->Vb; [48,52)->Gb gate.
__global__ __launch_bounds__(256) void mgemm2_fused_kernel(
    const unsigned short* __restrict__ A, const unsigned short* __restrict__ WALL,
    unsigned short* __restrict__ Qb, unsigned short* __restrict__ Kb,
    unsigned short* __restrict__ Vb, float* __restrict__ Gb)
{
  __shared__ __align__(16) unsigned short As[128 * 32];
  __shared__ __align__(16) unsigned short Bs[128 * 32];
  const int tid = threadIdx.x;
  const int bid = (int)(blockIdx.y * gridDim.x + blockIdx.x);
  const int xcd = bid & 7, local = bid >> 3;
  const int bm = xcd * 8 + (local & 7);
  const int bn = local >> 3;
  const int w = tid >> 6, l = tid & 63;
  const int wm = w & 1, wn = w >> 1;
  const int fr = l & 15, fq = l >> 4;

  f32x4 acc[4][4];
#pragma unroll
  for (int i = 0; i < 4; ++i)
#pragma unroll
    for (int j = 0; j < 4; ++j) acc[i][j] = (f32x4){0.f, 0.f, 0.f, 0.f};

  int prow[2], pcol[2];
#pragma unroll
  for (int j = 0; j < 2; ++j) {
    int p = w * 128 + j * 64 + l;
    prow[j] = p >> 2;
    pcol[j] = ((p & 3) ^ ((prow[j] >> 1) & 3)) * 8;
  }
  const size_t abase = (size_t)(bm * 128) * DM;
  const size_t bbase = (size_t)(bn * 128) * DM;

  for (int k0 = 0; k0 < DM; k0 += 32) {
#pragma unroll
    for (int j = 0; j < 2; ++j) {
      gload16(A + abase + (size_t)prow[j] * DM + k0 + pcol[j],
              &As[(w * 128 + j * 64) * 8]);
      gload16(WALL + bbase + (size_t)prow[j] * DM + k0 + pcol[j],
              &Bs[(w * 128 + j * 64) * 8]);
    }
    __syncthreads();
    bf16x8 af[4], bfr[4];
#pragma unroll
    for (int i = 0; i < 4; ++i) {
      int row = wm * 64 + i * 16 + fr;
      af[i] = *(const bf16x8*)&As[row * 32 + ((fq ^ ((row >> 1) & 3)) * 8)];
    }
#pragma unroll
    for (int j = 0; j < 4; ++j) {
      int row = wn * 64 + j * 16 + fr;
      bfr[j] = *(const bf16x8*)&Bs[row * 32 + ((fq ^ ((row >> 1) & 3)) * 8)];
    }
#pragma unroll
    for (int i = 0; i < 4; ++i)
#pragma unroll
      for (int j = 0; j < 4; ++j)
        acc[i][j] = __builtin_amdgcn_mfma_f32_16x16x32_bf16(af[i], bfr[j], acc[i][j], 0, 0, 0);
    __syncthreads();
  }

  // routing: uniform per block (128 | all boundaries)
  const int tgt = bn >> 4;                          // 0:Q 1:K 2:V 3:F
  unsigned short* oB = (tgt == 0) ? Qb : (tgt == 1) ? Kb : Vb;
  const int coff = tgt * 2048;

#pragma unroll
  for (int i = 0; i < 4; ++i) {
#pragma unroll
    for (int rr = 0; rr < 4; ++rr) {
      int row = bm * 128 + wm * 64 + i * 16 + fq * 4 + rr;
#pragma unroll
      for (int j = 0; j < 4; ++j) {
        int colg = bn * 128 + wn * 64 + j * 16 + fr;
        float val = acc[i][j][rr];
        if (tgt < 3) {
          oB[(size_t)row * 2048 + (colg - coff)] = f2us(swishf(val));
        } else {
          float ls = fminf(val, 0.f) - log1pf(expf(-fabsf(val)));
          Gb[(size_t)row * 512 + (colg - 6144)] = ls * 0.125f;
        }
      }
    }
  }
}

// ------------------------------------------------------------ MFMA GEMM ---
// (fallback tier: W in f32, converted in-kernel)
#define BM 128
#define BN 128
#define BK 32
#define LDSP 40

__global__ __launch_bounds__(256) void mgemm_kernel(
    const unsigned short* __restrict__ A, const float* __restrict__ W,
    unsigned short* __restrict__ outB, float* __restrict__ outF,
    int N, int mode)
{
  __shared__ __align__(16) unsigned short As[BM][LDSP];
  __shared__ __align__(16) unsigned short Bs[BN][LDSP];
  const int bn = blockIdx.x, bm = blockIdx.y, tid = threadIdx.x;
  const int w = tid >> 6, l = tid & 63;
  const int wm = w & 1, wn = w >> 1;
  const int fr = l & 15, fq = l >> 4;

  f32x4 acc[4][4];
#pragma unroll
  for (int i = 0; i < 4; ++i)
#pragma unroll
    for (int j = 0; j < 4; ++j) acc[i][j] = (f32x4){0.f, 0.f, 0.f, 0.f};

  for (int k0 = 0; k0 < DM; k0 += BK) {
#pragma unroll
    for (int s = 0; s < 2; ++s) {
      int chunk = tid + s * 256;
      int row = chunk >> 2;
      int cc = (chunk & 3) * 8;
      *(uint4*)&As[row][cc] =
          *(const uint4*)(A + (size_t)(bm * BM + row) * DM + k0 + cc);
    }
#pragma unroll
    for (int s = 0; s < 4; ++s) {
      int chunk = tid + s * 256;
      int row = chunk >> 3;
      int cc = (chunk & 7) * 4;
      float4 wv = *(const float4*)(W + (size_t)(bn * BN + row) * DM + k0 + cc);
      ushort4 w4;
      w4.x = f2us(wv.x); w4.y = f2us(wv.y); w4.z = f2us(wv.z); w4.w = f2us(wv.w);
      *(ushort4*)&Bs[row][cc] = w4;
    }
    __syncthreads();
    bf16x8 af[4], bfr[4];
#pragma unroll
    for (int i = 0; i < 4; ++i) af[i] = *(const bf16x8*)&As[wm * 64 + i * 16 + fr][fq * 8];
#pragma unroll
    for (int j = 0; j < 4; ++j) bfr[j] = *(const bf16x8*)&Bs[wn * 64 + j * 16 + fr][fq * 8];
#pragma unroll
    for (int i = 0; i < 4; ++i)
#pragma unroll
      for (int j = 0; j < 4; ++j)
        acc[i][j] = __builtin_amdgcn_mfma_f32_16x16x32_bf16(af[i], bfr[j], acc[i][j], 0, 0, 0);
    __syncthreads();
  }

#pragma unroll
  for (int i = 0; i < 4; ++i) {
#pragma unroll
    for (int rr = 0; rr < 4; ++rr) {
      int row = bm * BM + wm * 64 + i * 16 + fq * 4 + rr;
#pragma unroll
      for (int j = 0; j < 4; ++j) {
        int col = bn * BN + wn * 64 + j * 16 + fr;
        float val = acc[i][j][rr];
        size_t idx = (size_t)row * N + col;
        if (mode == MODE_SWISH)      outB[idx] = f2us(swishf(val));
        else if (mode == MODE_F32)   outF[idx] = val;
        else {  // MODE_GATE
          float ls = fminf(val, 0.f) - log1pf(expf(-fabsf(val)));
          outF[idx] = ls * 0.125f;
        }
      }
    }
  }
}

// ------------------------------------------------ Chunked GSA scan (C) ---
// Template: NCH chunks per block; INIT loads gk/gv from Sinit (f32).
// Fallback = <32,false>, grid 32.  Phase C = <4,true>, grid 256.
// (R4-proven form: no register prefetch — 128-VGPR cap forces spills.)
template<int NCH, bool INIT>
__global__ __launch_bounds__(512) void gsa_chunk_t(
    const unsigned short* __restrict__ Q, const unsigned short* __restrict__ K,
    const unsigned short* __restrict__ V, const float* __restrict__ G,
    float* __restrict__ O, const float* __restrict__ DK,
    const float* __restrict__ DV)
{
  // ---- LDS pool, phase-multiplexed (155.1 KiB) ----
  __shared__ __align__(16) char pool[158848];
  auto EB   = (unsigned short(*)[72])(pool + 0);       // e[i][m] bf16 (no XS)
  auto O1B  = (unsigned short(*)[72])(pool + 9216);    // o1[i][m] -> (GvB2 low)
  auto RB   = (unsigned short(*)[72])(pool + 18432);   // r[tau][m] -> (GvB2 hi)
  auto RT   = (unsigned short(*)[72])(pool + 27648);   // r^T[m][tau] -> wT
  auto SB   = (unsigned short(*)[72])(pool + 36864);   // S[i][tau] -> P[i][tau]
  auto UB   = (unsigned short(*)[72])(pool + 46080);   // u[i][m]
  float (*GS)[64] = (float(*)[64])(pool + 55296);      // g staging (f32)
  auto QT   = (unsigned short(*)[264])(pool + 55296);  // q tile [i][d]
  auto KTt2 = (unsigned short(*)[72])(pool + 55296);   // k^T rows d-128
  auto VTt2 = (unsigned short(*)[72])(pool + 55296);   // v^T rows u-128
  auto KT   = (unsigned short(*)[264])(pool + 89088);  // k tile [tau][d]
  auto VTt1 = (unsigned short(*)[72])(pool + 89088);   // v^T rows u<128
  auto GkB  = (unsigned short(*)[264])(pool + 122880); // Gk snapshot [m][d]
  auto KTt1 = (unsigned short(*)[72])(pool + 122880);  // k^T rows d<128
  auto GvB1 = (unsigned short(*)[72])(pool + 122880);  // Gv snapshot u<128
  auto GvB2 = (unsigned short(*)[72])(pool + 9216);    // Gv snapshot u>=128
  float (*red)[68] = (float(*)[68])(pool + 156672);    // prefix partials

  int bh, seg;
  if constexpr (INIT) { bh = (int)blockIdx.x >> 3; seg = (int)blockIdx.x & 7; }
  else                { bh = (int)blockIdx.x; seg = 0; }
  const int b = bh >> 3, h = bh & 7;
  const int tid = threadIdx.x;
  const int w = tid >> 6, l = tid & 63, fr = l & 15, fq = l >> 4;
  const int wlo = w & 3, whi = w >> 2;

  // gk[jj]: (m=wlo*16+fq*4+rr, d=(whi*8+jj)*16+fr)
  // gv[jj]: (u=ut*16+fq*4+rr, m=(jj&3)*16+fr), ut=(w>=4?8:0)+wlo*2+(jj>>2)
  f32x4 gk[8], gv[8];
  if constexpr (INIT) {
    const float* dk = DK + ((size_t)bh * 8 + seg) * 16384;
    const float* dv = DV + ((size_t)bh * 8 + seg) * 16384;
#pragma unroll
    for (int jj = 0; jj < 8; ++jj) {
      int ut = (w >= 4 ? 8 : 0) + wlo * 2 + (jj >> 2);
#pragma unroll
      for (int rr = 0; rr < 4; ++rr) {
        gk[jj][rr] = dk[(wlo * 16 + fq * 4 + rr) * 256 + (whi * 8 + jj) * 16 + fr];
        gv[jj][rr] = dv[(ut * 16 + fq * 4 + rr) * 64 + (jj & 3) * 16 + fr];
      }
    }
  } else {
#pragma unroll
    for (int jj = 0; jj < 8; ++jj) {
      gk[jj] = (f32x4){0.f, 0.f, 0.f, 0.f};
      gv[jj] = (f32x4){0.f, 0.f, 0.f, 0.f};
    }
  }

  for (int cl = 0; cl < NCH; ++cl) {
    const int c = seg * NCH + cl;
    const int rowbase = b * 2048 + c * 64;
    const bool upd = (cl != NCH - 1);  // last chunk's state update is dead

    // ---- ph1a: stage g tile; write Gk bf16 snapshot from regs ----
#pragma unroll
    for (int s = 0; s < 2; ++s) {
      int id = s * 512 + tid, row = id >> 4, mq = id & 15;
      *(float4*)&GS[row][mq * 4] =
          *(const float4*)&G[(size_t)(rowbase + row) * 512 + h * 64 + mq * 4];
    }
#pragma unroll
    for (int jj = 0; jj < 8; ++jj) {
      int dcol = (whi * 8 + jj) * 16 + fr;
#pragma unroll
      for (int rr = 0; rr < 4; ++rr) {
        int grow = wlo * 16 + fq * 4 + rr;
        GkB[grow][XS(grow, dcol)] = f2us(gk[jj][rr]);
      }
    }
    __syncthreads();

    // ---- ph1b: per-8-row partial sums of g (prefix stage 1) ----
    {
      float ps = 0.f;
#pragma unroll
      for (int j = 0; j < 8; ++j) ps += GS[w * 8 + j][l];
      red[w][l] = ps;
    }
    __syncthreads();

    // ---- ph1c: cum, e, r (EB, RB, RT) ----
    {
      float cum = 0.f;
      for (int g2 = 0; g2 < w; ++g2) cum += red[g2][l];
#pragma unroll
      for (int j = 0; j < 8; ++j) {
        int i = w * 8 + j;
        float gval = GS[i][l];
        cum += gval;
        float e = expf(cum);
        float s_ = 1.f - expf(gval);
        float r_ = s_ / e;
        EB[i][l] = f2us(e);
        RB[i][XS(i, l)] = f2us(r_);
        RT[l][XS(l, i)] = f2us(r_);
      }
    }
    __syncthreads();

    // ---- ph2: stage q,k tiles (GS dead) ----
#pragma unroll
    for (int s = 0; s < 4; ++s) {
      int id = s * 512 + tid, row = id >> 5, cc = (id & 31) * 8;
      int sc = XS(row, cc);
      size_t gb = (size_t)(rowbase + row) * 2048 + h * 256 + cc;
      *(uint4*)&QT[row][sc] = *(const uint4*)(Q + gb);
      *(uint4*)&KT[row][sc] = *(const uint4*)(K + gb);
    }
    __syncthreads();

    // ---- ph3: S = QK^T (->SB, causal) and o1 += Q Gk^T ----
    f32x4 o1acc[2];
    o1acc[0] = (f32x4){0.f, 0.f, 0.f, 0.f};
    o1acc[1] = (f32x4){0.f, 0.f, 0.f, 0.f};
    {
      f32x4 sacc[2];
      sacc[0] = (f32x4){0.f, 0.f, 0.f, 0.f};
      sacc[1] = (f32x4){0.f, 0.f, 0.f, 0.f};
      int ar_ = wlo * 16 + fr;
#pragma unroll
      for (int kk = 0; kk < 8; ++kk) {
        bf16x8 aq = *(const bf16x8*)&QT[ar_][XS(ar_, kk * 32 + fq * 8)];
#pragma unroll
        for (int t2 = 0; t2 < 2; ++t2) {
          int tj = (whi + 2 * t2) * 16 + fr;
          int bc = XS(tj, kk * 32 + fq * 8);
          bf16x8 bk = *(const bf16x8*)&KT[tj][bc];
          sacc[t2] = __builtin_amdgcn_mfma_f32_16x16x32_bf16(aq, bk, sacc[t2], 0, 0, 0);
          bf16x8 bg = *(const bf16x8*)&GkB[tj][bc];
          o1acc[t2] = __builtin_amdgcn_mfma_f32_16x16x32_bf16(aq, bg, o1acc[t2], 0, 0, 0);
        }
      }
#pragma unroll
      for (int t2 = 0; t2 < 2; ++t2)
#pragma unroll
        for (int rr = 0; rr < 4; ++rr) {
          int i = wlo * 16 + fq * 4 + rr;
          int tau = (whi + 2 * t2) * 16 + fr;
          SB[i][XS(i, tau)] = f2us(tau <= i ? sacc[t2][rr] : 0.f);
        }
    }
    __syncthreads();

    // ---- ph4: o1 += S r (intra); write O1B = e * o1 ----
    {
      int ar_ = wlo * 16 + fr;
#pragma unroll
      for (int kk = 0; kk < 2; ++kk) {
        bf16x8 as = *(const bf16x8*)&SB[ar_][XS(ar_, kk * 32 + fq * 8)];
#pragma unroll
        for (int t2 = 0; t2 < 2; ++t2) {
          int tj = (whi + 2 * t2) * 16 + fr;
          bf16x8 br = *(const bf16x8*)&RT[tj][XS(tj, kk * 32 + fq * 8)];
          o1acc[t2] = __builtin_amdgcn_mfma_f32_16x16x32_bf16(as, br, o1acc[t2], 0, 0, 0);
        }
      }
#pragma unroll
      for (int t2 = 0; t2 < 2; ++t2)
#pragma unroll
        for (int rr = 0; rr < 4; ++rr) {
          int i = wlo * 16 + fq * 4 + rr;
          int m = (whi + 2 * t2) * 16 + fr;
          O1B[i][XS(i, m)] = f2us(u2f(EB[i][m]) * o1acc[t2][rr]);
        }
    }
    __syncthreads();

    // ---- ph5: softmax rows -> u = qv*e (UB);  wT = e63*r^T in place ----
    {
      int i = tid >> 3, mq = tid & 7;
      int sc = XS(i, mq * 8);
      uint4 raw = *(const uint4*)&O1B[i][sc];
      const unsigned short* rp = (const unsigned short*)&raw;
      float x[8];
#pragma unroll
      for (int j = 0; j < 8; ++j) x[j] = u2f(rp[j]);
      float mx = x[0];
#pragma unroll
      for (int j = 1; j < 8; ++j) mx = fmaxf(mx, x[j]);
      mx = fmaxf(mx, __shfl_xor(mx, 1, 64));
      mx = fmaxf(mx, __shfl_xor(mx, 2, 64));
      mx = fmaxf(mx, __shfl_xor(mx, 4, 64));
      float ex[8], sum = 0.f;
#pragma unroll
      for (int j = 0; j < 8; ++j) { ex[j] = expf(x[j] - mx); sum += ex[j]; }
      sum += __shfl_xor(sum, 1, 64);
      sum += __shfl_xor(sum, 2, 64);
      sum += __shfl_xor(sum, 4, 64);
      float inv = 1.f / sum;
      unsigned short up[8];
#pragma unroll
      for (int j = 0; j < 8; ++j)
        up[j] = f2us(ex[j] * inv * u2f(EB[i][mq * 8 + j]));
      *(uint4*)&UB[i][sc] = *(uint4*)up;
    }
    {
      int m2 = tid >> 3, tq = tid & 7;
      int sc = XS(m2, tq * 8);
      float e63 = u2f(EB[63][m2]);
      uint4 raw = *(const uint4*)&RT[m2][sc];
      const unsigned short* rp = (const unsigned short*)&raw;
      unsigned short ow[8];
#pragma unroll
      for (int j = 0; j < 8; ++j) ow[j] = f2us(u2f(rp[j]) * e63);
      *(uint4*)&RT[m2][sc] = *(uint4*)ow;
    }
    __syncthreads();

    // ---- ph6: P^T = r u^T -> SB (transposed write, causal); K->KTt1 ----
    {
      f32x4 pacc[2];
      pacc[0] = (f32x4){0.f, 0.f, 0.f, 0.f};
      pacc[1] = (f32x4){0.f, 0.f, 0.f, 0.f};
      int ar_ = wlo * 16 + fr;
#pragma unroll
      for (int kk = 0; kk < 2; ++kk) {
        bf16x8 ar = *(const bf16x8*)&RB[ar_][XS(ar_, kk * 32 + fq * 8)];
#pragma unroll
        for (int t2 = 0; t2 < 2; ++t2) {
          int tj = (whi + 2 * t2) * 16 + fr;
          bf16x8 bu = *(const bf16x8*)&UB[tj][XS(tj, kk * 32 + fq * 8)];
          pacc[t2] = __builtin_amdgcn_mfma_f32_16x16x32_bf16(ar, bu, pacc[t2], 0, 0, 0);
        }
      }
#pragma unroll
      for (int t2 = 0; t2 < 2; ++t2)
#pragma unroll
        for (int rr = 0; rr < 4; ++rr) {
          int tau = wlo * 16 + fq * 4 + rr;
          int i = (whi + 2 * t2) * 16 + fr;
          SB[i][XS(i, tau)] = f2us(tau <= i ? pacc[t2][rr] : 0.f);  // PB
        }
    }
    if (upd) {
#pragma unroll
      for (int s = 0; s < 2; ++s) {
        int id = s * 512 + tid, d8 = id & 15, tau = id >> 4;
        uint4 raw = *(const uint4*)&KT[tau][XS(tau, d8 * 8)];
        const unsigned short* rp = (const unsigned short*)&raw;
#pragma unroll
        for (int j = 0; j < 8; ++j) {
          int trow = d8 * 8 + j;
          KTt1[trow][XS(trow, tau)] = rp[j];
        }
      }
    }
    __syncthreads();

    // ---- ph7a: waves0-3: Gk update (d<128);  waves4-7: K->KTt2 ----
    if (upd) {
      if (w < 4) {
        float e63r[4];
#pragma unroll
        for (int rr = 0; rr < 4; ++rr) e63r[rr] = u2f(EB[63][wlo * 16 + fq * 4 + rr]);
        int wr = wlo * 16 + fr;
        bf16x8 aw0 = *(const bf16x8*)&RT[wr][XS(wr, fq * 8)];
        bf16x8 aw1 = *(const bf16x8*)&RT[wr][XS(wr, 32 + fq * 8)];
#pragma unroll
        for (int jj = 0; jj < 8; ++jj) {
#pragma unroll
          for (int rr = 0; rr < 4; ++rr) gk[jj][rr] *= e63r[rr];
          int kr = jj * 16 + fr;
          bf16x8 bk0 = *(const bf16x8*)&KTt1[kr][XS(kr, fq * 8)];
          bf16x8 bk1 = *(const bf16x8*)&KTt1[kr][XS(kr, 32 + fq * 8)];
          gk[jj] = __builtin_amdgcn_mfma_f32_16x16x32_bf16(aw0, bk0, gk[jj], 0, 0, 0);
          gk[jj] = __builtin_amdgcn_mfma_f32_16x16x32_bf16(aw1, bk1, gk[jj], 0, 0, 0);
        }
      } else {
#pragma unroll
        for (int s = 0; s < 4; ++s) {
          int id = s * 256 + (tid - 256), d8 = id & 15, tau = id >> 4;
          uint4 raw = *(const uint4*)&KT[tau][XS(tau, 128 + d8 * 8)];
          const unsigned short* rp = (const unsigned short*)&raw;
#pragma unroll
          for (int j = 0; j < 8; ++j) {
            int trow = d8 * 8 + j;
            KTt2[trow][XS(trow, tau)] = rp[j];
          }
        }
      }
    }
    __syncthreads();

    // ---- ph7b: waves4-7: Gk update (d>=128); waves0-3: VTt1 + GvB1 ----
    if (upd && w >= 4) {
      float e63r[4];
#pragma unroll
      for (int rr = 0; rr < 4; ++rr) e63r[rr] = u2f(EB[63][wlo * 16 + fq * 4 + rr]);
      int wr = wlo * 16 + fr;
      bf16x8 aw0 = *(const bf16x8*)&RT[wr][XS(wr, fq * 8)];
      bf16x8 aw1 = *(const bf16x8*)&RT[wr][XS(wr, 32 + fq * 8)];
#pragma unroll
      for (int jj = 0; jj < 8; ++jj) {
#pragma unroll
        for (int rr = 0; rr < 4; ++rr) gk[jj][rr] *= e63r[rr];
        int kr = jj * 16 + fr;
        bf16x8 bk0 = *(const bf16x8*)&KTt2[kr][XS(kr, fq * 8)];
        bf16x8 bk1 = *(const bf16x8*)&KTt2[kr][XS(kr, 32 + fq * 8)];
        gk[jj] = __builtin_amdgcn_mfma_f32_16x16x32_bf16(aw0, bk0, gk[jj], 0, 0, 0);
        gk[jj] = __builtin_amdgcn_mfma_f32_16x16x32_bf16(aw1, bk1, gk[jj], 0, 0, 0);
      }
    }
    if (w < 4) {
#pragma unroll
      for (int s = 0; s < 4; ++s) {
        int id = s * 256 + tid, u8 = id & 15, tau = id >> 4;
        uint4 raw = *(const uint4*)(V + (size_t)(rowbase + tau) * 2048 + h * 256 + u8 * 8);
        const unsigned short* rp = (const unsigned short*)&raw;
#pragma unroll
        for (int j = 0; j < 8; ++j) {
          int trow = u8 * 8 + j;
          VTt1[trow][XS(trow, tau)] = rp[j];
        }
      }
#pragma unroll
      for (int jj = 0; jj < 8; ++jj) {
        int u0 = (wlo * 2 + (jj >> 2)) * 16 + fq * 4;
        int m = (jj & 3) * 16 + fr;
#pragma unroll
        for (int rr = 0; rr < 4; ++rr) {
          int grow = u0 + rr;
          GvB1[grow][XS(grow, m)] = f2us(gv[jj][rr]);
        }
      }
    }
    __syncthreads();

    // ---- ph8: o(u<128) -> O ; w<4: Gv upd h1; VTt2 stage; w>=4: GvB2 ----
    {
      int pr = wlo * 16 + fr;
      bf16x8 ap0 = *(const bf16x8*)&SB[pr][XS(pr, fq * 8)];
      bf16x8 ap1 = *(const bf16x8*)&SB[pr][XS(pr, 32 + fq * 8)];
      bf16x8 au0 = *(const bf16x8*)&UB[pr][XS(pr, fq * 8)];
      bf16x8 au1 = *(const bf16x8*)&UB[pr][XS(pr, 32 + fq * 8)];
#pragma unroll
      for (int oo = 0; oo < 4; ++oo) {
        int ut = whi * 4 + oo;
        int vr = ut * 16 + fr;
        f32x4 oa = (f32x4){0.f, 0.f, 0.f, 0.f};
        bf16x8 bv0 = *(const bf16x8*)&VTt1[vr][XS(vr, fq * 8)];
        bf16x8 bv1 = *(const bf16x8*)&VTt1[vr][XS(vr, 32 + fq * 8)];
        bf16x8 bg0 = *(const bf16x8*)&GvB1[vr][XS(vr, fq * 8)];
        bf16x8 bg1 = *(const bf16x8*)&GvB1[vr][XS(vr, 32 + fq * 8)];
        oa = __builtin_amdgcn_mfma_f32_16x16x32_bf16(ap0, bv0, oa, 0, 0, 0);
        oa = __builtin_amdgcn_mfma_f32_16x16x32_bf16(ap1, bv1, oa, 0, 0, 0);
        oa = __builtin_amdgcn_mfma_f32_16x16x32_bf16(au0, bg0, oa, 0, 0, 0);
        oa = __builtin_amdgcn_mfma_f32_16x16x32_bf16(au1, bg1, oa, 0, 0, 0);
#pragma unroll
        for (int rr = 0; rr < 4; ++rr)
          O[(size_t)(rowbase + wlo * 16 + fq * 4 + rr) * 2048 + h * 256 + ut * 16 + fr] = oa[rr];
      }
    }
#pragma unroll
    for (int s = 0; s < 2; ++s) {
      int id = s * 512 + tid, u8 = id & 15, tau = id >> 4;
      uint4 raw = *(const uint4*)(V + (size_t)(rowbase + tau) * 2048 + h * 256 + 128 + u8 * 8);
      const unsigned short* rp = (const unsigned short*)&raw;
#pragma unroll
      for (int j = 0; j < 8; ++j) {
        int trow = u8 * 8 + j;
        VTt2[trow][XS(trow, tau)] = rp[j];
      }
    }
    if (w < 4) {
      if (upd) {
#pragma unroll
        for (int jj = 0; jj < 8; ++jj) {
          int ut = wlo * 2 + (jj >> 2), mt = jj & 3;
          float e63v = u2f(EB[63][mt * 16 + fr]);
#pragma unroll
          for (int rr = 0; rr < 4; ++rr) gv[jj][rr] *= e63v;
          int vr = ut * 16 + fr, br_ = mt * 16 + fr;
          bf16x8 av0 = *(const bf16x8*)&VTt1[vr][XS(vr, fq * 8)];
          bf16x8 av1 = *(const bf16x8*)&VTt1[vr][XS(vr, 32 + fq * 8)];
          bf16x8 bw0 = *(const bf16x8*)&RT[br_][XS(br_, fq * 8)];
          bf16x8 bw1 = *(const bf16x8*)&RT[br_][XS(br_, 32 + fq * 8)];
          gv[jj] = __builtin_amdgcn_mfma_f32_16x16x32_bf16(av0, bw0, gv[jj], 0, 0, 0);
          gv[jj] = __builtin_amdgcn_mfma_f32_16x16x32_bf16(av1, bw1, gv[jj], 0, 0, 0);
        }
      }
    } else {
#pragma unroll
      for (int jj = 0; jj < 8; ++jj) {
        int u0 = (wlo * 2 + (jj >> 2)) * 16 + fq * 4;
        int m = (jj & 3) * 16 + fr;
#pragma unroll
        for (int rr = 0; rr < 4; ++rr) {
          int grow = u0 + rr;
          GvB2[grow][XS(grow, m)] = f2us(gv[jj][rr]);
        }
      }
    }
    __syncthreads();

    // ---- ph9: o(u>=128) -> O ; waves4-7: Gv upd h2 ----
    {
      int pr = wlo * 16 + fr;
      bf16x8 ap0 = *(const bf16x8*)&SB[pr][XS(pr, fq * 8)];
      bf16x8 ap1 = *(const bf16x8*)&SB[pr][XS(pr, 32 + fq * 8)];
      bf16x8 au0 = *(const bf16x8*)&UB[pr][XS(pr, fq * 8)];
      bf16x8 au1 = *(const bf16x8*)&UB[pr][XS(pr, 32 + fq * 8)];
#pragma unroll
      for (int oo = 0; oo < 4; ++oo) {
        int utl = whi * 4 + oo;  // local u-tile (global ut = 8+utl)
        int vr = utl * 16 + fr;
        f32x4 oa = (f32x4){0.f, 0.f, 0.f, 0.f};
        bf16x8 bv0 = *(const bf16x8*)&VTt2[vr][XS(vr, fq * 8)];
        bf16x8 bv1 = *(const bf16x8*)&VTt2[vr][XS(vr, 32 + fq * 8)];
        bf16x8 bg0 = *(const bf16x8*)&GvB2[vr][XS(vr, fq * 8)];
        bf16x8 bg1 = *(const bf16x8*)&GvB2[vr][XS(vr, 32 + fq * 8)];
        oa = __builtin_amdgcn_mfma_f32_16x16x32_bf16(ap0, bv0, oa, 0, 0, 0);
        oa = __builtin_amdgcn_mfma_f32_16x16x32_bf16(ap1, bv1, oa, 0, 0, 0);
        oa = __builtin_amdgcn_mfma_f32_16x16x32_bf16(au0, bg0, oa, 0, 0, 0);
        oa = __builtin_amdgcn_mfma_f32_16x16x32_bf16(au1, bg1, oa, 0, 0, 0);
#pragma unroll
        for (int rr = 0; rr < 4; ++rr)
          O[(size_t)(rowbase + wlo * 16 + fq * 4 + rr) * 2048 + h * 256 + 128 + utl * 16 + fr] = oa[rr];
      }
    }
    if (upd && w >= 4) {
#pragma unroll
      for (int jj = 0; jj < 8; ++jj) {
        int utl = wlo * 2 + (jj >> 2), mt = jj & 3;
        float e63v = u2f(EB[63][mt * 16 + fr]);
#pragma unroll
        for (int rr = 0; rr < 4; ++rr) gv[jj][rr] *= e63v;
        int vr = utl * 16 + fr, br_ = mt * 16 + fr;
        bf16x8 av0 = *(const bf16x8*)&VTt2[vr][XS(vr, fq * 8)];
        bf16x8 av1 = *(const bf16x8*)&VTt2[vr][XS(vr, 32 + fq * 8)];
        bf16x8 bw0 = *(const bf16x8*)&RT[br_][XS(br_, fq * 8)];
        bf16x8 bw1 = *(const bf16x8*)&RT[br_][XS(br_, 32 + fq * 8)];
        gv[jj] = __builtin_amdgcn_mfma_f32_16x16x32_bf16(av0, bw0, gv[jj], 0, 0, 0);
        gv[jj] = __builtin_amdgcn_mfma_f32_16x16x32_bf16(av1, bw1, gv[jj], 0, 0, 0);
      }
    }
    __syncthreads();
  }
}

// --------------------------------------------- Phase A: segment deltas ---
__global__ __launch_bounds__(512) void gsa_segA_kernel(
    const unsigned short* __restrict__ K, const unsigned short* __restrict__ V,
    const float* __restrict__ G, float* __restrict__ DK, float* __restrict__ DV,
    float* __restrict__ ES)
{
  __shared__ __align__(16) char pool[135552];
  float (*GS)[64] = (float(*)[64])(pool);             // 16384
  float (*red)[68] = (float(*)[68])(pool + 16384);    // 2176
  auto RT   = (unsigned short(*)[72])(pool + 18560);  // 9216
  float* e63f = (float*)(pool + 27776);               // 256
  auto KT   = (unsigned short(*)[264])(pool + 28032); // 33792
  auto KTt1 = (unsigned short(*)[72])(pool + 61824);  // 18432
  auto KTt2 = (unsigned short(*)[72])(pool + 80256);
  auto VTt1 = (unsigned short(*)[72])(pool + 98688);
  auto VTt2 = (unsigned short(*)[72])(pool + 117120); // end 135552

  const int bh = (int)blockIdx.x >> 3, seg = (int)blockIdx.x & 7;
  const int b = bh >> 3, h = bh & 7;
  const int tid = threadIdx.x;
  const int w = tid >> 6, l = tid & 63, fr = l & 15, fq = l >> 4;
  const int wlo = w & 3, whi = w >> 2;

  f32x4 gk[8], gv[8];
#pragma unroll
  for (int jj = 0; jj < 8; ++jj) {
    gk[jj] = (f32x4){0.f, 0.f, 0.f, 0.f};
    gv[jj] = (f32x4){0.f, 0.f, 0.f, 0.f};
  }
  float gsum = 0.f;  // valid on w==7 threads

  for (int cl = 0; cl < 4; ++cl) {
    const int rowbase = b * 2048 + (seg * 4 + cl) * 64;

    // ph1: stage G + K
#pragma unroll
    for (int s = 0; s < 2; ++s) {
      int id = s * 512 + tid, row = id >> 4, mq = id & 15;
      *(float4*)&GS[row][mq * 4] =
          *(const float4*)&G[(size_t)(rowbase + row) * 512 + h * 64 + mq * 4];
    }
#pragma unroll
    for (int s = 0; s < 4; ++s) {
      int id = s * 512 + tid, row = id >> 5, cc = (id & 31) * 8;
      *(uint4*)&KT[row][XS(row, cc)] =
          *(const uint4*)(K + (size_t)(rowbase + row) * 2048 + h * 256 + cc);
    }
    __syncthreads();

    // ph2: prefix partials
    {
      float ps = 0.f;
#pragma unroll
      for (int j = 0; j < 8; ++j) ps += GS[w * 8 + j][l];
      red[w][l] = ps;
    }
    __syncthreads();

    // ph3: cum -> RT (r^T), e63, segment g-sum
    {
      float cum = 0.f;
      for (int g2 = 0; g2 < w; ++g2) cum += red[g2][l];
#pragma unroll
      for (int j = 0; j < 8; ++j) {
        int i = w * 8 + j;
        float gval = GS[i][l];
        cum += gval;
        float e = expf(cum);
        float r_ = (1.f - expf(gval)) / e;
        RT[l][XS(l, i)] = f2us(r_);
      }
      if (w == 7) { gsum += cum; e63f[l] = expf(cum); }
    }
    __syncthreads();

    // ph4: RT *= e63 (-> w^T); K transposes; V transposes (from global)
    {
      int m2 = tid >> 3, tq = tid & 7;
      int sc = XS(m2, tq * 8);
      float e63 = e63f[m2];
      uint4 raw = *(const uint4*)&RT[m2][sc];
      const unsigned short* rp = (const unsigned short*)&raw;
      unsigned short ow[8];
#pragma unroll
      for (int j = 0; j < 8; ++j) ow[j] = f2us(u2f(rp[j]) * e63);
      *(uint4*)&RT[m2][sc] = *(uint4*)ow;
    }
#pragma unroll
    for (int s = 0; s < 2; ++s) {
      int id = s * 512 + tid, d8 = id & 15, tau = id >> 4;
      uint4 raw1 = *(const uint4*)&KT[tau][XS(tau, d8 * 8)];
      uint4 raw2 = *(const uint4*)&KT[tau][XS(tau, 128 + d8 * 8)];
      const unsigned short* rp1 = (const unsigned short*)&raw1;
      const unsigned short* rp2 = (const unsigned short*)&raw2;
#pragma unroll
      for (int j = 0; j < 8; ++j) {
        int trow = d8 * 8 + j;
        KTt1[trow][XS(trow, tau)] = rp1[j];
        KTt2[trow][XS(trow, tau)] = rp2[j];
      }
    }
#pragma unroll
    for (int s = 0; s < 2; ++s) {
      int id = s * 512 + tid, u8 = id & 15, tau = id >> 4;
      size_t gb = (size_t)(rowbase + tau) * 2048 + h * 256 + u8 * 8;
      uint4 raw1 = *(const uint4*)(V + gb);
      uint4 raw2 = *(const uint4*)(V + gb + 128);
      const unsigned short* rp1 = (const unsigned short*)&raw1;
      const unsigned short* rp2 = (const unsigned short*)&raw2;
#pragma unroll
      for (int j = 0; j < 8; ++j) {
        int trow = u8 * 8 + j;
        VTt1[trow][XS(trow, tau)] = rp1[j];
        VTt2[trow][XS(trow, tau)] = rp2[j];
      }
    }
    __syncthreads();

    // ph5: gk += w^T K ; gv += V^T w
    {
      float e63r[4];
#pragma unroll
      for (int rr = 0; rr < 4; ++rr) e63r[rr] = e63f[wlo * 16 + fq * 4 + rr];
      int wr = wlo * 16 + fr;
      bf16x8 aw0 = *(const bf16x8*)&RT[wr][XS(wr, fq * 8)];
      bf16x8 aw1 = *(const bf16x8*)&RT[wr][XS(wr, 32 + fq * 8)];
      auto KTx = (w < 4) ? KTt1 : KTt2;
#pragma unroll
      for (int jj = 0; jj < 8; ++jj) {
#pragma unroll
        for (int rr = 0; rr < 4; ++rr) gk[jj][rr] *= e63r[rr];
        int kr = jj * 16 + fr;
        bf16x8 bk0 = *(const bf16x8*)&KTx[kr][XS(kr, fq * 8)];
        bf16x8 bk1 = *(const bf16x8*)&KTx[kr][XS(kr, 32 + fq * 8)];
        gk[jj] = __builtin_amdgcn_mfma_f32_16x16x32_bf16(aw0, bk0, gk[jj], 0, 0, 0);
        gk[jj] = __builtin_amdgcn_mfma_f32_16x16x32_bf16(aw1, bk1, gk[jj], 0, 0, 0);
      }
      auto VTx = (w < 4) ? VTt1 : VTt2;
#pragma unroll
      for (int jj = 0; jj < 8; ++jj) {
        int utl = wlo * 2 + (jj >> 2), mt = jj & 3;
        float e63v = e63f[mt * 16 + fr];
#pragma unroll
        for (int rr = 0; rr < 4; ++rr) gv[jj][rr] *= e63v;
        int vr = utl * 16 + fr, br_ = mt * 16 + fr;
        bf16x8 av0 = *(const bf16x8*)&VTx[vr][XS(vr, fq * 8)];
        bf16x8 av1 = *(const bf16x8*)&VTx[vr][XS(vr, 32 + fq * 8)];
        bf16x8 bw0 = *(const bf16x8*)&RT[br_][XS(br_, fq * 8)];
        bf16x8 bw1 = *(const bf16x8*)&RT[br_][XS(br_, 32 + fq * 8)];
        gv[jj] = __builtin_amdgcn_mfma_f32_16x16x32_bf16(av0, bw0, gv[jj], 0, 0, 0);
        gv[jj] = __builtin_amdgcn_mfma_f32_16x16x32_bf16(av1, bw1, gv[jj], 0, 0, 0);
      }
    }
    __syncthreads();
  }

  // write deltas + segment decay
  float* dk = DK + ((size_t)bh * 8 + seg) * 16384;
  float* dv = DV + ((size_t)bh * 8 + seg) * 16384;
#pragma unroll
  for (int jj = 0; jj < 8; ++jj) {
    int ut = (w >= 4 ? 8 : 0) + wlo * 2 + (jj >> 2);
#pragma unroll
    for (int rr = 0; rr < 4; ++rr) {
      dk[(wlo * 16 + fq * 4 + rr) * 256 + (whi * 8 + jj) * 16 + fr] = gk[jj][rr];
      dv[(ut * 16 + fq * 4 + rr) * 64 + (jj & 3) * 16 + fr] = gv[jj][rr];
    }
  }
  if (w == 7) ES[((size_t)bh * 8 + seg) * 64 + l] = expf(gsum);
}

// ------------------------------------------- Phase B: prefix combine ---
__global__ __launch_bounds__(1024) void gsa_segB_kernel(
    float* __restrict__ DK, float* __restrict__ DV, const float* __restrict__ ES)
{
  const int bh = blockIdx.x, tid = threadIdx.x;
  __shared__ float es[8][64];
  if (tid < 512) es[tid >> 6][tid & 63] = ES[(size_t)bh * 512 + tid];
  __syncthreads();
  float* dk = DK + (size_t)bh * 8 * 16384;
  float* dv = DV + (size_t)bh * 8 * 16384;
  for (int k = 0; k < 16; ++k) {
    int e = k * 1024 + tid;
    int m = e >> 8;                 // DK: e = m*256 + d
    float S = 0.f;
#pragma unroll
    for (int s = 0; s < 8; ++s) {
      float d = dk[s * 16384 + e];
      dk[s * 16384 + e] = S;
      S = fmaf(S, es[s][m], d);
    }
  }
  for (int k = 0; k < 16; ++k) {
    int e = k * 1024 + tid;
    int m = e & 63;                 // DV: e = u*64 + m
    float S = 0.f;
#pragma unroll
    for (int s = 0; s < 8; ++s) {
      float d = dv[s * 16384 + e];
      dv[s * 16384 + e] = S;
      S = fmaf(S, es[s][m], d);
    }
  }
}

// ------------------------------------------------------------- sentinel ---
__global__ __launch_bounds__(256) void fillf_kernel(float* o, float v) {
  o[(size_t)blockIdx.x * 256 + threadIdx.x] = v;
}

// --------------------------------------------------------------- launch ---
extern "C" void kernel_launch(void* const* d_in, const int* in_sizes, int n_in,
                              void* d_out, int out_size, void* d_ws, size_t ws_size,
                              hipStream_t stream)
{
  const float* hidden   = (const float*)d_in[0];
  const float* norm_w   = (const float*)d_in[1];
  const float* q_w      = (const float*)d_in[2];
  const float* k_w      = (const float*)d_in[3];
  const float* v_w      = (const float*)d_in[4];
  const float* f_w      = (const float*)d_in[5];
  const float* g_norm_w = (const float*)d_in[6];
  const float* o_w      = (const float*)d_in[7];

  float* dout = (float*)d_out;
  char* ws = (char*)d_ws;
  const size_t SZB = (size_t)ROWS * DM * 2;        // 32MiB bf16 activation
  const size_t SZG = (size_t)ROWS * 512 * 4;       // 16MiB f32 gates
  const size_t NEED = 4 * SZB + SZG;               // 144MiB
  const size_t SZD = (size_t)32 * 8 * 16384 * 4;   // 16MiB per delta array
  const size_t NEED_BIG = NEED + 2 * SZD + (size_t)32 * 8 * 64 * 4;
  const size_t SZWB = (size_t)DM * DM * 2;         // 8MiB bf16 weight
  const size_t SZWF = (size_t)512 * DM * 2;        // 2MiB bf16 f-weight
  const size_t NEED_W = NEED_BIG + 4 * SZWB + SZWF;

  if (ws_size < NEED) {
    fillf_kernel<<<65536, 256, 0, stream>>>(dout, 123.0f);
    return;
  }

  unsigned short* XN = (unsigned short*)(ws);      // xnorm, later o_act
  unsigned short* Qb = (unsigned short*)(ws + SZB);
  unsigned short* Kb = (unsigned short*)(ws + 2 * SZB);
  unsigned short* Vb = (unsigned short*)(ws + 3 * SZB);
  float* Gb          = (float*)(ws + 4 * SZB);
  float* DK          = (float*)(ws + NEED);
  float* DV          = DK + (size_t)32 * 8 * 16384;
  float* ES          = DV + (size_t)32 * 8 * 16384;
  // weight layout: WQ,WK,WV,WF contiguous (fused GEMM), then WO.
  unsigned short* WQ = (unsigned short*)(ws + NEED_BIG);
  unsigned short* WK = WQ + (size_t)2048 * 2048;
  unsigned short* WV = WK + (size_t)2048 * 2048;
  unsigned short* WF = WV + (size_t)2048 * 2048;
  unsigned short* WO = WF + (size_t)512 * 2048;

  xnorm_kernel<<<ROWS, 256, 0, stream>>>(hidden, norm_w, XN);

  if (ws_size >= NEED_W) {
    // weight pre-conversion (f32 -> bf16, RNE; same rounding as before)
    wconv_kernel<<<2048, 256, 0, stream>>>(q_w, WQ);
    wconv_kernel<<<2048, 256, 0, stream>>>(k_w, WK);
    wconv_kernel<<<2048, 256, 0, stream>>>(v_w, WV);
    wconv_kernel<<<512, 256, 0, stream>>>(f_w, WF);
    wconv_kernel<<<2048, 256, 0, stream>>>(o_w, WO);

    // fused Q/K/V/F projection: N=6656, grid 52x64 (nwg=3328 %8==0)
    mgemm2_fused_kernel<<<dim3(52, 64), 256, 0, stream>>>(XN, WQ, Qb, Kb, Vb, Gb);
  } else {
    mgemm_kernel<<<dim3(16, 64), 256, 0, stream>>>(XN, q_w, Qb, nullptr, 2048, MODE_SWISH);
    mgemm_kernel<<<dim3(16, 64), 256, 0, stream>>>(XN, k_w, Kb, nullptr, 2048, MODE_SWISH);
    mgemm_kernel<<<dim3(16, 64), 256, 0, stream>>>(XN, v_w, Vb, nullptr, 2048, MODE_SWISH);
    mgemm_kernel<<<dim3(4, 64), 256, 0, stream>>>(XN, f_w, nullptr, Gb, 512, MODE_GATE);
  }

  if (ws_size >= NEED_BIG) {
    gsa_segA_kernel<<<256, 512, 0, stream>>>(Kb, Vb, Gb, DK, DV, ES);
    gsa_segB_kernel<<<32, 1024, 0, stream>>>(DK, DV, ES);
    gsa_chunk_t<4, true><<<256, 512, 0, stream>>>(Qb, Kb, Vb, Gb, dout, DK, DV);
  } else {
    gsa_chunk_t<32, false><<<32, 512, 0, stream>>>(Qb, Kb, Vb, Gb, dout, nullptr, nullptr);
  }

  oact_norm_kernel<<<ROWS, 256, 0, stream>>>(dout, g_norm_w, XN);

  if (ws_size >= NEED_W)
    mgemm2_kernel<<<dim3(16, 64), 256, 0, stream>>>(XN, WO, nullptr, dout, 2048, MODE_F32);
  else
    mgemm_kernel<<<dim3(16, 64), 256, 0, stream>>>(XN, o_w, nullptr, dout, 2048, MODE_F32);
}